// Round 10
// baseline (1802.253 us; speedup 1.0000x reference)
//
#include <hip/hip_runtime.h>
#include <math.h>

#define E_CNT 200000
typedef unsigned short bfu;
typedef unsigned short u16;
typedef __attribute__((ext_vector_type(8))) short bh8;
typedef __attribute__((ext_vector_type(4))) float f4;

__device__ __forceinline__ float gelu_f(float x) {
    return 0.5f * x * (1.0f + erff(x * 0.70710678118654752f));
}
__device__ __forceinline__ float bf2f(bfu u) { return __uint_as_float(((unsigned)u) << 16); }
__device__ __forceinline__ bfu f2bf(float f) {
    unsigned u = __float_as_uint(f);
    unsigned r = u + 0x7FFFu + ((u >> 16) & 1u);
    return (bfu)(r >> 16);
}
__device__ __forceinline__ int rsrc_of(int r) {
    const int a[8] = {0, 1, 2, 1, 3, 0, 3, 2}; return a[r];
}
__device__ __forceinline__ int rdst_of(int r) {
    const int a[8] = {1, 0, 1, 2, 0, 3, 2, 3}; return a[r];
}
__device__ __forceinline__ int rpoff_of(int r) {
    const int a[9] = {0, 20001, 50002, 70003, 95004, 125005, 175006, 200007, 250008};
    return a[r];
}

__global__ __launch_bounds__(256) void fill_val(float* p, int n, float v) {
    int i = blockIdx.x * 256 + threadIdx.x;
    if (i < n) p[i] = v;
}

// ---- one-shot f32->bf16 weight/emb converts ----
__global__ __launch_bounds__(256) void cvt_pack(
    const float* __restrict__ out_W, const float* __restrict__ kqv_W,
    const float* __restrict__ fin_W, const float* __restrict__ fout_W,
    const float* __restrict__ event_emb,
    bfu* __restrict__ OWB, bfu* __restrict__ KWB, bfu* __restrict__ FINWB,
    bfu* __restrict__ FOUTWB, bfu* __restrict__ EVB)
{
    int i = blockIdx.x * 256 + threadIdx.x;
    const float* src; bfu* dst; size_t so, dox;
    if (i < 49152) { src = out_W; dst = OWB; so = (size_t)i * 4; dox = so; }
    else if (i < 98304) {
        int j = i - 49152; int m = j >> 12; int o = (j & 4095) * 4;
        src = kqv_W; dst = KWB;
        so = (size_t)m * 3 * 16384 + o; dox = (size_t)m * 16384 + o;
    }
    else if (i < 135168) { int j = i - 98304; src = fin_W; dst = FINWB; so = (size_t)j * 4; dox = so; }
    else if (i < 147456) { int j = i - 135168; src = fout_W; dst = FOUTWB; so = (size_t)j * 4; dox = so; }
    else if (i < 1747456) { int j = i - 147456; src = event_emb; dst = EVB; so = (size_t)j * 4; dox = so; }
    else return;
    float4 v = *(const float4*)(src + so);
    uint2 u;
    u.x = ((unsigned)f2bf(v.x)) | (((unsigned)f2bf(v.y)) << 16);
    u.y = ((unsigned)f2bf(v.z)) | (((unsigned)f2bf(v.w)) << 16);
    *(uint2*)(dst + dox) = u;
}

// ---- CSR build ----
__global__ __launch_bounds__(256) void hist_all(const int* __restrict__ edges, int* __restrict__ rp) {
    int i = blockIdx.x * 256 + threadIdx.x;
    if (i >= 8 * E_CNT) return;
    int r = i / E_CNT, e = i - r * E_CNT;
    int d = edges[(size_t)(2 * r + 1) * E_CNT + e];
    atomicAdd(&rp[rpoff_of(r) + d + 1], 1);
}
__global__ __launch_bounds__(1024) void scan_part(int* __restrict__ a, int* __restrict__ part, int n) {
    __shared__ int lds[1024];
    int t = threadIdx.x, i = blockIdx.x * 1024 + t;
    int v = (i < n) ? a[i] : 0;
    lds[t] = v;
    __syncthreads();
    for (int off = 1; off < 1024; off <<= 1) {
        int u = (t >= off) ? lds[t - off] : 0;
        __syncthreads();
        lds[t] += u;
        __syncthreads();
    }
    if (i < n) a[i] = lds[t];
    if (t == 1023) part[blockIdx.x] = lds[1023];
}
__global__ __launch_bounds__(256) void scan_tot(int* __restrict__ part, int nb) {
    __shared__ int lds[256];
    int t = threadIdx.x;
    int v = (t < nb) ? part[t] : 0;
    lds[t] = v;
    __syncthreads();
    for (int off = 1; off < 256; off <<= 1) {
        int u = (t >= off) ? lds[t - off] : 0;
        __syncthreads();
        lds[t] += u;
        __syncthreads();
    }
    if (t < nb) part[t] = lds[t];
}
__global__ __launch_bounds__(1024) void scan_add(int* __restrict__ a, const int* __restrict__ part, int n) {
    int b = blockIdx.x + 1;
    int i = b * 1024 + threadIdx.x;
    if (i < n) a[i] += part[b - 1];
}
__global__ __launch_bounds__(256) void scatter_all(
    const int* __restrict__ edges, const int* __restrict__ RP,
    int* __restrict__ cur, u16* __restrict__ SIDX) {
    int i = blockIdx.x * 256 + threadIdx.x;
    if (i >= 8 * E_CNT) return;
    int r = i / E_CNT, e = i - r * E_CNT;
    int d = edges[(size_t)(2 * r + 1) * E_CNT + e];
    int pos = RP[rpoff_of(r) + d] + atomicAdd(&cur[r * 50000 + d], 1);
    SIDX[pos] = (u16)edges[(size_t)(2 * r) * E_CNT + e];
}

// ---- input projection (f32[N,64] -> relu -> bf16[N,128]) ----
__global__ __launch_bounds__(256) void proj_gemm(
    const float* __restrict__ X, const float* __restrict__ W,
    const float* __restrict__ bias, bfu* __restrict__ Y, int N)
{
    __shared__ __align__(16) float Wt[32][132];
    __shared__ __align__(16) float Xt[32][36];
    const int tid = threadIdx.x;
    const int r0 = blockIdx.x * 32;
    const int rg = tid >> 5, cg = tid & 31;
    float acc[4][4];
    #pragma unroll
    for (int i = 0; i < 4; ++i)
        #pragma unroll
        for (int j = 0; j < 4; ++j) acc[i][j] = 0.f;
    for (int c0 = 0; c0 < 64; c0 += 32) {
        __syncthreads();
        #pragma unroll
        for (int k = 0; k < 4; ++k) {
            int v = tid + k * 256;
            int j = v >> 3, c4 = (v & 7) * 4;
            float4 w = *(const float4*)(W + (size_t)j * 64 + c0 + c4);
            Wt[c4 + 0][j] = w.x; Wt[c4 + 1][j] = w.y;
            Wt[c4 + 2][j] = w.z; Wt[c4 + 3][j] = w.w;
        }
        {
            int rr = tid >> 3, c4 = (tid & 7) * 4;
            int row = r0 + rr;
            float4 x = make_float4(0.f, 0.f, 0.f, 0.f);
            if (row < N) x = *(const float4*)(X + (size_t)row * 64 + c0 + c4);
            Xt[c4 + 0][rr] = x.x; Xt[c4 + 1][rr] = x.y;
            Xt[c4 + 2][rr] = x.z; Xt[c4 + 3][rr] = x.w;
        }
        __syncthreads();
        #pragma unroll
        for (int cc = 0; cc < 32; ++cc) {
            float4 xv = *(const float4*)(&Xt[cc][rg * 4]);
            float4 wv = *(const float4*)(&Wt[cc][cg * 4]);
            #pragma unroll
            for (int i = 0; i < 4; ++i) {
                float xs = (i == 0) ? xv.x : (i == 1) ? xv.y : (i == 2) ? xv.z : xv.w;
                acc[i][0] = fmaf(xs, wv.x, acc[i][0]);
                acc[i][1] = fmaf(xs, wv.y, acc[i][1]);
                acc[i][2] = fmaf(xs, wv.z, acc[i][2]);
                acc[i][3] = fmaf(xs, wv.w, acc[i][3]);
            }
        }
    }
    float4 bv = *(const float4*)(bias + cg * 4);
    #pragma unroll
    for (int ri = 0; ri < 4; ++ri) {
        int row = r0 + rg * 4 + ri;
        if (row >= N) continue;
        float y0 = fmaxf(acc[ri][0] + bv.x, 0.f);
        float y1 = fmaxf(acc[ri][1] + bv.y, 0.f);
        float y2 = fmaxf(acc[ri][2] + bv.z, 0.f);
        float y3 = fmaxf(acc[ri][3] + bv.w, 0.f);
        uint2 u;
        u.x = ((unsigned)f2bf(y0)) | (((unsigned)f2bf(y1)) << 16);
        u.y = ((unsigned)f2bf(y2)) | (((unsigned)f2bf(y3)) << 16);
        *(uint2*)(Y + (size_t)row * 128 + cg * 4) = u;
    }
}

// ---- merged relation-folded weight builder ----
__global__ __launch_bounds__(256) void build_rel(
    const float* __restrict__ kqvW_l, const float* __restrict__ kqvb_l,
    const float* __restrict__ a_l, const float* __restrict__ m_l,
    bfu* __restrict__ WQAB, float* __restrict__ BQA,
    bfu* __restrict__ WVMB, float* __restrict__ BVM)
{
    __shared__ float As[32][33];
    __shared__ float Ws[32][129];
    int tid = threadIdx.x;
    int b = blockIdx.x;
    if (b < 32) {
        int r = b >> 2, h = b & 3;
        int dt = rdst_of(r);
        const float* Wq = kqvW_l + ((size_t)dt * 3 + 1) * 16384;
        const float* bq = kqvb_l + ((size_t)dt * 3 + 1) * 128;
        const float* A = a_l + (size_t)r * 4096 + h * 1024;
        for (int v = tid; v < 1024; v += 256) As[v >> 5][v & 31] = A[v];
        for (int v = tid; v < 4096; v += 256)
            Ws[v >> 7][v & 127] = Wq[(size_t)(h * 32 + (v >> 7)) * 128 + (v & 127)];
        __syncthreads();
        int c = tid & 127, half = tid >> 7;
        for (int d = half; d < 32; d += 2) {
            float acc = 0.f;
            #pragma unroll
            for (int f = 0; f < 32; ++f) acc = fmaf(As[d][f], Ws[f][c], acc);
            WQAB[((size_t)r * 128 + h * 32 + d) * 128 + c] = f2bf(acc);
        }
        if (tid < 32) {
            int d = tid;
            float acc = 0.f;
            #pragma unroll
            for (int f = 0; f < 32; ++f) acc = fmaf(As[d][f], bq[h * 32 + f], acc);
            BQA[(size_t)r * 128 + h * 32 + d] = acc;
        }
    } else {
        int bb2 = b - 32;
        int r = bb2 >> 2, h = bb2 & 3;
        int st = rsrc_of(r);
        const float* Wv = kqvW_l + ((size_t)st * 3 + 2) * 16384;
        const float* bv = kqvb_l + ((size_t)st * 3 + 2) * 128;
        const float* M = m_l + (size_t)r * 4096 + h * 1024;
        for (int v = tid; v < 1024; v += 256) As[v >> 5][v & 31] = M[v];  // As holds M here
        for (int v = tid; v < 4096; v += 256)
            Ws[v >> 7][v & 127] = Wv[(size_t)(h * 32 + (v >> 7)) * 128 + (v & 127)];
        __syncthreads();
        int c = tid & 127, half = tid >> 7;
        for (int f = half; f < 32; f += 2) {
            float acc = 0.f;
            #pragma unroll
            for (int d = 0; d < 32; ++d) acc = fmaf(As[d][f], Ws[d][c], acc);
            WVMB[((size_t)r * 128 + h * 32 + f) * 128 + c] = f2bf(acc);
        }
        if (tid < 32) {
            int f = tid;
            float acc = 0.f;
            #pragma unroll
            for (int d = 0; d < 32; ++d) acc = fmaf(As[d][f], bv[h * 32 + d], acc);
            BVM[(size_t)r * 128 + h * 32 + f] = acc;
        }
    }
}

// ---- batched MFMA GEMM: up to 9 descriptors, 32 rows/wave, 128 rows/block ----
struct GDesc { const bfu* X; const bfu* W; const float* bias; bfu* Y; int N; int ldy; int bend; };
struct GBatch { GDesc d[9]; };

__global__ __launch_bounds__(256) void mgemm_batch(GBatch gb) {
    int b = blockIdx.x;
    int gi = 0;
    #pragma unroll
    for (int k = 0; k < 8; ++k) gi += (b >= gb.d[k].bend) ? 1 : 0;
    const bfu* X = gb.d[0].X; const bfu* W = gb.d[0].W;
    const float* bi = gb.d[0].bias; bfu* Y = gb.d[0].Y;
    int N = gb.d[0].N, ldy = gb.d[0].ldy, bstart = 0;
    #pragma unroll
    for (int k = 1; k < 9; ++k) {
        if (gi == k) {
            X = gb.d[k].X; W = gb.d[k].W; bi = gb.d[k].bias; Y = gb.d[k].Y;
            N = gb.d[k].N; ldy = gb.d[k].ldy; bstart = gb.d[k - 1].bend;
        }
    }
    int bloc = b - bstart;
    const int tid = threadIdx.x;
    const int wave = tid >> 6, lane = tid & 63;
    const int row16 = lane & 15, kgrp = lane >> 4;
    const int r_base = bloc * 128 + wave * 32;
    f4 acc[2][8];
    #pragma unroll
    for (int t = 0; t < 2; ++t)
        #pragma unroll
        for (int n = 0; n < 8; ++n) acc[t][n] = (f4){0.f, 0.f, 0.f, 0.f};
    bh8 az = {0, 0, 0, 0, 0, 0, 0, 0};
    #pragma unroll
    for (int kb = 0; kb < 4; ++kb) {
        int ar0 = r_base + row16, ar1 = r_base + 16 + row16;
        bh8 a0 = az, a1 = az;
        if (ar0 < N) a0 = *(const bh8*)(X + (size_t)ar0 * 128 + kb * 32 + kgrp * 8);
        if (ar1 < N) a1 = *(const bh8*)(X + (size_t)ar1 * 128 + kb * 32 + kgrp * 8);
        #pragma unroll
        for (int n = 0; n < 8; ++n) {
            bh8 bv = *(const bh8*)(W + (size_t)(n * 16 + row16) * 128 + kb * 32 + kgrp * 8);
            acc[0][n] = __builtin_amdgcn_mfma_f32_16x16x32_bf16(a0, bv, acc[0][n], 0, 0, 0);
            acc[1][n] = __builtin_amdgcn_mfma_f32_16x16x32_bf16(a1, bv, acc[1][n], 0, 0, 0);
        }
    }
    #pragma unroll
    for (int t = 0; t < 2; ++t) {
        const int crow0 = r_base + t * 16 + kgrp * 4;
        #pragma unroll
        for (int n = 0; n < 8; ++n) {
            int col = n * 16 + row16;
            float bn = bi[col];
            #pragma unroll
            for (int j = 0; j < 4; ++j) {
                int row = crow0 + j;
                if (row < N) Y[(size_t)row * ldy + col] = f2bf(acc[t][n][j] + bn);
            }
        }
    }
}

// ---- dual-relation flash aggregation: ONE wave per node, 4B loads ----
// lane l: features c0=2l, c1=2l+1; head h = l>>4 (16-lane groups).
// Single online softmax chain across both relations. Output = gelu(a/d) bf16.
// ACC aliases QAA (row-owner-safe: wave reads its QAA row before writing it).
__global__ __launch_bounds__(256) void agg_dual(
    const bfu* QAA, const bfu* __restrict__ QAB,
    const bfu* __restrict__ KA, const bfu* __restrict__ VMA,
    const bfu* __restrict__ KB, const bfu* __restrict__ VMB,
    const int* __restrict__ rpA, const int* __restrict__ rpB,
    const u16* __restrict__ sidx,
    const float* __restrict__ prlA, const float* __restrict__ prlB,
    bfu* ACC, int Nn)
{
    int n = blockIdx.x * 4 + (threadIdx.x >> 6);
    if (n >= Nn) return;
    int l = threadIdx.x & 63;
    int h = l >> 4;
    const float scl = 0.17677669529663687f;

    float m = -3.0e38f, d = 0.f, a0 = 0.f, a1 = 0.f;

    auto upd = [&](float s, unsigned vu) {
        float nm = fmaxf(m, s);
        float sc = __expf(m - nm), w = __expf(s - nm);
        d = d * sc + w;
        a0 = fmaf(w, bf2f((bfu)vu), a0 * sc);
        a1 = fmaf(w, bf2f((bfu)(vu >> 16)), a1 * sc);
        m = nm;
    };

    // ---- relation A ----
    {
        unsigned qu = *(const unsigned*)(QAA + (size_t)n * 128 + 2 * l);
        float q0 = bf2f((bfu)qu), q1 = bf2f((bfu)(qu >> 16));
        float ph = prlA[h] * scl;
        int i = rpA[n], e1 = rpA[n + 1];
        for (; i + 1 < e1; i += 2) {
            int sa = sidx[i], sb = sidx[i + 1];
            unsigned ka = *(const unsigned*)(KA + (size_t)sa * 128 + 2 * l);
            unsigned kb = *(const unsigned*)(KA + (size_t)sb * 128 + 2 * l);
            unsigned va = *(const unsigned*)(VMA + (size_t)sa * 128 + 2 * l);
            unsigned vb = *(const unsigned*)(VMA + (size_t)sb * 128 + 2 * l);
            float s0 = fmaf(bf2f((bfu)ka), q0, bf2f((bfu)(ka >> 16)) * q1);
            float s1 = fmaf(bf2f((bfu)kb), q0, bf2f((bfu)(kb >> 16)) * q1);
            #pragma unroll
            for (int off = 1; off <= 8; off <<= 1) {
                s0 += __shfl_xor(s0, off);
                s1 += __shfl_xor(s1, off);
            }
            upd(s0 * ph, va);
            upd(s1 * ph, vb);
        }
        if (i < e1) {
            int sa = sidx[i];
            unsigned ka = *(const unsigned*)(KA + (size_t)sa * 128 + 2 * l);
            unsigned va = *(const unsigned*)(VMA + (size_t)sa * 128 + 2 * l);
            float s0 = fmaf(bf2f((bfu)ka), q0, bf2f((bfu)(ka >> 16)) * q1);
            #pragma unroll
            for (int off = 1; off <= 8; off <<= 1) s0 += __shfl_xor(s0, off);
            upd(s0 * ph, va);
        }
    }
    // ---- relation B (same chain continues) ----
    {
        unsigned qu = *(const unsigned*)(QAB + (size_t)n * 128 + 2 * l);
        float q0 = bf2f((bfu)qu), q1 = bf2f((bfu)(qu >> 16));
        float ph = prlB[h] * scl;
        int i = rpB[n], e1 = rpB[n + 1];
        for (; i + 1 < e1; i += 2) {
            int sa = sidx[i], sb = sidx[i + 1];
            unsigned ka = *(const unsigned*)(KB + (size_t)sa * 128 + 2 * l);
            unsigned kb = *(const unsigned*)(KB + (size_t)sb * 128 + 2 * l);
            unsigned va = *(const unsigned*)(VMB + (size_t)sa * 128 + 2 * l);
            unsigned vb = *(const unsigned*)(VMB + (size_t)sb * 128 + 2 * l);
            float s0 = fmaf(bf2f((bfu)ka), q0, bf2f((bfu)(ka >> 16)) * q1);
            float s1 = fmaf(bf2f((bfu)kb), q0, bf2f((bfu)(kb >> 16)) * q1);
            #pragma unroll
            for (int off = 1; off <= 8; off <<= 1) {
                s0 += __shfl_xor(s0, off);
                s1 += __shfl_xor(s1, off);
            }
            upd(s0 * ph, va);
            upd(s1 * ph, vb);
        }
        if (i < e1) {
            int sa = sidx[i];
            unsigned ka = *(const unsigned*)(KB + (size_t)sa * 128 + 2 * l);
            unsigned va = *(const unsigned*)(VMB + (size_t)sa * 128 + 2 * l);
            float s0 = fmaf(bf2f((bfu)ka), q0, bf2f((bfu)(ka >> 16)) * q1);
            #pragma unroll
            for (int off = 1; off <= 8; off <<= 1) s0 += __shfl_xor(s0, off);
            upd(s0 * ph, va);
        }
    }
    float rd = 1.f / fmaxf(d, 1e-16f);
    float y0 = gelu_f(a0 * rd);
    float y1 = gelu_f(a1 * rd);
    unsigned ou = ((unsigned)f2bf(y0)) | (((unsigned)f2bf(y1)) << 16);
    *(unsigned*)(ACC + (size_t)n * 128 + 2 * l) = ou;
}

// ---- layer epilogue: plain A (already gelu'd); out-proj; skip+LN+relu; bf16 out ----
__global__ __launch_bounds__(256) void mgemm_epi_layer(
    const bfu* __restrict__ A, const bfu* __restrict__ W, const float* __restrict__ bias,
    const bfu* __restrict__ Xr, const float* __restrict__ skp,
    const float* __restrict__ g, const float* __restrict__ bb,
    bfu* __restrict__ Y, int N)
{
    const int tid = threadIdx.x;
    const int wave = tid >> 6, lane = tid & 63;
    const int row16 = lane & 15, kgrp = lane >> 4;
    const int r_base = blockIdx.x * 64 + wave * 16;
    const int arow = r_base + row16;
    f4 acc[8];
    #pragma unroll
    for (int n = 0; n < 8; ++n) acc[n] = (f4){0.f, 0.f, 0.f, 0.f};
    bh8 az = {0, 0, 0, 0, 0, 0, 0, 0};
    #pragma unroll
    for (int kb = 0; kb < 4; ++kb) {
        bh8 a = az;
        if (arow < N) a = *(const bh8*)(A + (size_t)arow * 128 + kb * 32 + kgrp * 8);
        #pragma unroll
        for (int n = 0; n < 8; ++n) {
            bh8 bv = *(const bh8*)(W + (size_t)(n * 16 + row16) * 128 + kb * 32 + kgrp * 8);
            acc[n] = __builtin_amdgcn_mfma_f32_16x16x32_bf16(a, bv, acc[n], 0, 0, 0);
        }
    }
    const int crow0 = r_base + kgrp * 4;
    float sg = 1.f / (1.f + expf(-skp[0]));
    float z[8][4];
    #pragma unroll
    for (int n = 0; n < 8; ++n) {
        float bn = bias[n * 16 + row16];
        #pragma unroll
        for (int j = 0; j < 4; ++j) z[n][j] = acc[n][j] + bn;
    }
    #pragma unroll
    for (int j = 0; j < 4; ++j) {
        int row = crow0 + j;
        if (row >= N) continue;
        #pragma unroll
        for (int n = 0; n < 8; ++n) {
            float xr = bf2f(Xr[(size_t)row * 128 + n * 16 + row16]);
            z[n][j] = sg * z[n][j] + (1.f - sg) * xr + xr;
        }
    }
    float s[4], q[4];
    #pragma unroll
    for (int j = 0; j < 4; ++j) {
        s[j] = 0.f; q[j] = 0.f;
        #pragma unroll
        for (int n = 0; n < 8; ++n) { s[j] += z[n][j]; q[j] += z[n][j] * z[n][j]; }
    }
    #pragma unroll
    for (int off = 1; off <= 8; off <<= 1) {
        #pragma unroll
        for (int j = 0; j < 4; ++j) {
            s[j] += __shfl_xor(s[j], off);
            q[j] += __shfl_xor(q[j], off);
        }
    }
    #pragma unroll
    for (int j = 0; j < 4; ++j) {
        int row = crow0 + j;
        if (row >= N) continue;
        float mean = s[j] * (1.f / 128.f);
        float var = q[j] * (1.f / 128.f) - mean * mean;
        float inv = rsqrtf(var + 1e-5f);
        #pragma unroll
        for (int n = 0; n < 8; ++n) {
            int col = n * 16 + row16;
            float y = (z[n][j] - mean) * inv * g[col] + bb[col];
            Y[(size_t)row * 128 + col] = f2bf(fmaxf(y, 0.f));
        }
    }
}

// ---- fusion final: out-proj; LN; f32 out ----
__global__ __launch_bounds__(256) void mgemm_epi_ln(
    const bfu* __restrict__ X, const bfu* __restrict__ W, const float* __restrict__ bias,
    const float* __restrict__ g, const float* __restrict__ bb,
    float* __restrict__ Y, int N)
{
    const int tid = threadIdx.x;
    const int wave = tid >> 6, lane = tid & 63;
    const int row16 = lane & 15, kgrp = lane >> 4;
    const int r_base = blockIdx.x * 64 + wave * 16;
    const int arow = r_base + row16;
    f4 acc[8];
    #pragma unroll
    for (int n = 0; n < 8; ++n) acc[n] = (f4){0.f, 0.f, 0.f, 0.f};
    bh8 az = {0, 0, 0, 0, 0, 0, 0, 0};
    #pragma unroll
    for (int kb = 0; kb < 4; ++kb) {
        bh8 a = az;
        if (arow < N) a = *(const bh8*)(X + (size_t)arow * 128 + kb * 32 + kgrp * 8);
        #pragma unroll
        for (int n = 0; n < 8; ++n) {
            bh8 bv = *(const bh8*)(W + (size_t)(n * 16 + row16) * 128 + kb * 32 + kgrp * 8);
            acc[n] = __builtin_amdgcn_mfma_f32_16x16x32_bf16(a, bv, acc[n], 0, 0, 0);
        }
    }
    const int crow0 = r_base + kgrp * 4;
    float z[8][4];
    #pragma unroll
    for (int n = 0; n < 8; ++n) {
        float bn = bias[n * 16 + row16];
        #pragma unroll
        for (int j = 0; j < 4; ++j) z[n][j] = acc[n][j] + bn;
    }
    float s[4], q[4];
    #pragma unroll
    for (int j = 0; j < 4; ++j) {
        s[j] = 0.f; q[j] = 0.f;
        #pragma unroll
        for (int n = 0; n < 8; ++n) { s[j] += z[n][j]; q[j] += z[n][j] * z[n][j]; }
    }
    #pragma unroll
    for (int off = 1; off <= 8; off <<= 1) {
        #pragma unroll
        for (int j = 0; j < 4; ++j) {
            s[j] += __shfl_xor(s[j], off);
            q[j] += __shfl_xor(q[j], off);
        }
    }
    #pragma unroll
    for (int j = 0; j < 4; ++j) {
        int row = crow0 + j;
        if (row >= N) continue;
        float mean = s[j] * (1.f / 128.f);
        float var = q[j] * (1.f / 128.f) - mean * mean;
        float inv = rsqrtf(var + 1e-5f);
        #pragma unroll
        for (int n = 0; n < 8; ++n) {
            int col = n * 16 + row16;
            Y[(size_t)row * 128 + col] = (z[n][j] - mean) * inv * g[col] + bb[col];
        }
    }
}

// ---- fusion attention (3 tokens, 4 heads), wave per node, bf16 out ----
__global__ __launch_bounds__(256) void attn_fuse(
    const bfu* __restrict__ QKV, bfu* __restrict__ OM, int M)
{
    int n = blockIdx.x * 4 + (threadIdx.x >> 6);
    int l = threadIdx.x & 63;
    if (n >= M) return;
    const bfu* base = QKV + (size_t)n * 1152;
    float q[3][2], k[3][2], v[3][2];
    #pragma unroll
    for (int p = 0; p < 3; ++p) {
        q[p][0] = bf2f(base[(0 * 3 + p) * 128 + l]);
        q[p][1] = bf2f(base[(0 * 3 + p) * 128 + l + 64]);
        k[p][0] = bf2f(base[(1 * 3 + p) * 128 + l]);
        k[p][1] = bf2f(base[(1 * 3 + p) * 128 + l + 64]);
        v[p][0] = bf2f(base[(2 * 3 + p) * 128 + l]);
        v[p][1] = bf2f(base[(2 * 3 + p) * 128 + l + 64]);
    }
    float lgA[3][3], lgB[3][3];
    #pragma unroll
    for (int qi = 0; qi < 3; ++qi)
        #pragma unroll
        for (int ki = 0; ki < 3; ++ki) {
            float s0 = q[qi][0] * k[ki][0];
            float s1 = q[qi][1] * k[ki][1];
            #pragma unroll
            for (int off = 1; off <= 16; off <<= 1) {
                s0 += __shfl_xor(s0, off);
                s1 += __shfl_xor(s1, off);
            }
            lgA[qi][ki] = s0 * 0.17677669529663687f;
            lgB[qi][ki] = s1 * 0.17677669529663687f;
        }
    float oA = 0.f, oB = 0.f;
    #pragma unroll
    for (int qi = 0; qi < 3; ++qi) {
        float mA = fmaxf(lgA[qi][0], fmaxf(lgA[qi][1], lgA[qi][2]));
        float e0 = __expf(lgA[qi][0] - mA), e1 = __expf(lgA[qi][1] - mA), e2 = __expf(lgA[qi][2] - mA);
        float rd = 1.f / (e0 + e1 + e2);
        oA += (e0 * v[0][0] + e1 * v[1][0] + e2 * v[2][0]) * rd;
        float mB = fmaxf(lgB[qi][0], fmaxf(lgB[qi][1], lgB[qi][2]));
        float f0 = __expf(lgB[qi][0] - mB), f1 = __expf(lgB[qi][1] - mB), f2 = __expf(lgB[qi][2] - mB);
        float rdB = 1.f / (f0 + f1 + f2);
        oB += (f0 * v[0][1] + f1 * v[1][1] + f2 * v[2][1]) * rdB;
    }
    OM[(size_t)n * 128 + l] = f2bf(oA * (1.f / 3.f));
    OM[(size_t)n * 128 + l + 64] = f2bf(oB * (1.f / 3.f));
}

extern "C" void kernel_launch(void* const* d_in, const int* in_sizes, int n_in,
                              void* d_out, int out_size, void* d_ws, size_t ws_size,
                              hipStream_t stream)
{
    const float* x_pest   = (const float*)d_in[0];
    const float* x_dis    = (const float*)d_in[1];
    const float* x_plant  = (const float*)d_in[2];
    const int*   edges    = (const int*)d_in[3];
    const float* proj_W   = (const float*)d_in[4];
    const float* proj_b   = (const float*)d_in[5];
    const float* event_emb= (const float*)d_in[6];
    const float* kqv_W    = (const float*)d_in[7];
    const float* kqv_b    = (const float*)d_in[8];
    const float* out_W    = (const float*)d_in[9];
    const float* out_b    = (const float*)d_in[10];
    const float* skip     = (const float*)d_in[11];
    const float* a_rel    = (const float*)d_in[12];
    const float* m_rel    = (const float*)d_in[13];
    const float* p_rel    = (const float*)d_in[14];
    const float* blk_ln_g = (const float*)d_in[15];
    const float* blk_ln_b = (const float*)d_in[16];
    const float* fin_W    = (const float*)d_in[17];
    const float* fin_b    = (const float*)d_in[18];
    const float* fout_W   = (const float*)d_in[19];
    const float* fout_b   = (const float*)d_in[20];
    const float* f_ln_g   = (const float*)d_in[21];
    const float* f_ln_b   = (const float*)d_in[22];
    float* out = (float*)d_out;

    static const int NT[4]  = {30000, 20000, 25000, 50000};
    static const int OFF[4] = {0, 30000, 50000, 75000};
    static const int RPOFF[9] = {0, 20001, 50002, 70003, 95004, 125005, 175006, 200007, 250008};
    static const int DG[4][2][2] = { {{1,1},{4,3}}, {{0,0},{2,2}}, {{3,1},{6,3}}, {{5,0},{7,2}} };

    char* wsb = (char*)d_ws;
    size_t ob = 0;
    auto alc = [&](size_t bytes) -> void* {
        void* p = wsb + ob; ob += (bytes + 255) & ~(size_t)255; return p;
    };
    bfu* LK0  = (bfu*)alc((size_t)75000 * 128 * 2);
    bfu* LK1  = (bfu*)alc((size_t)75000 * 128 * 2);
    bfu* POOL = (bfu*)alc((size_t)210000 * 128 * 2);   // QA_A/QA_B/K/VM pool; fusion QKV; CUR
    bfu* WQAB = (bfu*)alc((size_t)8 * 16384 * 2);
    float* BQA = (float*)alc((size_t)8 * 128 * 4);
    bfu* WVMB = (bfu*)alc((size_t)8 * 16384 * 2);
    float* BVM = (float*)alc((size_t)8 * 128 * 4);
    bfu* KWB  = (bfu*)alc((size_t)12 * 16384 * 2);
    bfu* OWB  = (bfu*)alc((size_t)12 * 16384 * 2);
    bfu* FINWB = (bfu*)alc((size_t)3 * 49152 * 2);
    bfu* FOUTWB = (bfu*)alc((size_t)3 * 16384 * 2);
    int* RP   = (int*)alc((size_t)250008 * 4);
    int* PART = (int*)alc(1024);
    u16* SIDX = (u16*)alc((size_t)8 * E_CNT * 2);
    if (ws_size < ob) {
        fill_val<<<(out_size + 255) / 256, 256, 0, stream>>>(out, out_size, 1e30f);
        return;
    }
    int* CUR = (int*)POOL;       // CSR counters (1.6MB), used before pool
    bfu* QKVf = POOL;            // fusion QKV (CH*1152*2 <= 46.08MB <= 53.76MB)
    bfu* OMB  = POOL + (size_t)20000 * 1152;  // attn out (5.12MB, ends at 51.2MB)

    // d_out overlay (time-disjoint): EVB [0,12.8M); XB [12.8,32.0M); L2F [19.2,38.4M)
    bfu* EVB = (bfu*)out;
    bfu* XB  = (bfu*)((char*)out + 12800000);
    bfu* L2F = (bfu*)((char*)out + 19200000);

    cvt_pack<<<(1747456 + 255) / 256, 256, 0, stream>>>(
        out_W, kqv_W, fin_W, fout_W, event_emb, OWB, KWB, FINWB, FOUTWB, EVB);

    // ---- CSR build ----
    hipMemsetAsync(RP, 0, (size_t)250008 * 4, stream);
    const int eg8 = (8 * E_CNT + 255) / 256;
    hist_all<<<eg8, 256, 0, stream>>>(edges, RP);
    scan_part<<<245, 1024, 0, stream>>>(RP, PART, 250008);
    scan_tot<<<1, 256, 0, stream>>>(PART, 245);
    scan_add<<<244, 1024, 0, stream>>>(RP, PART, 250008);
    hipMemsetAsync(CUR, 0, (size_t)8 * 50000 * 4, stream);
    scatter_all<<<eg8, 256, 0, stream>>>(edges, RP, CUR, SIDX);

    // ---- input projections ----
    const float* xin0[3] = {x_pest, x_dis, x_plant};
    for (int t = 0; t < 3; ++t) {
        proj_gemm<<<(NT[t] + 31) / 32, 256, 0, stream>>>(
            xin0[t], proj_W + (size_t)t * 8192, proj_b + (size_t)t * 128,
            XB + (size_t)OFF[t] * 128, NT[t]);
    }

    auto launch_batch = [&](GDesc* ds, int cnt) {
        GBatch gb;
        int acc = 0;
        for (int i = 0; i < cnt; ++i) {
            gb.d[i] = ds[i];
            acc += (ds[i].N + 127) / 128;
            gb.d[i].bend = acc;
        }
        for (int i = cnt; i < 9; ++i) { gb.d[i] = gb.d[cnt - 1]; gb.d[i].bend = acc; }
        mgemm_batch<<<acc, 256, 0, stream>>>(gb);
    };

    for (int l = 0; l < 3; ++l) {
        const float* kqvW_l = kqv_W + (size_t)l * 12 * 16384;
        const float* kqvb_l = kqv_b + (size_t)l * 12 * 128;
        build_rel<<<64, 256, 0, stream>>>(kqvW_l, kqvb_l,
            a_rel + (size_t)l * 8 * 4096, m_rel + (size_t)l * 8 * 4096,
            WQAB, BQA, WVMB, BVM);

        auto feat_ptr = [&](int tt) -> const bfu* {
            if (tt == 3) return EVB;
            if (l == 0) return XB + (size_t)OFF[tt] * 128;
            return (l == 1 ? LK0 : LK1) + (size_t)OFF[tt] * 128;
        };

        int nord = (l == 2) ? 3 : 4;
        for (int dt = 0; dt < nord; ++dt) {
            int Ndt = NT[dt];
            int rA = DG[dt][0][0], sA = DG[dt][0][1];
            int rB = DG[dt][1][0], sB = DG[dt][1][1];
            int NsA = NT[sA], NsB = NT[sB];
            // pool layout (rows of 128 bf16): QA_A | QA_B | K_A | VM_A | K_B | VM_B
            bfu* QA_A = POOL;
            bfu* QA_B = QA_A + (size_t)Ndt * 128;
            bfu* K_A  = QA_B + (size_t)Ndt * 128;
            bfu* VM_A = K_A + (size_t)NsA * 128;
            bfu* K_B  = VM_A + (size_t)NsA * 128;
            bfu* VM_B = K_B + (size_t)NsB * 128;

            GDesc ds[6];
            ds[0] = { feat_ptr(dt), WQAB + (size_t)rA * 16384, BQA + (size_t)rA * 128, QA_A, Ndt, 128, 0 };
            ds[1] = { feat_ptr(dt), WQAB + (size_t)rB * 16384, BQA + (size_t)rB * 128, QA_B, Ndt, 128, 0 };
            ds[2] = { feat_ptr(sA), KWB + (size_t)(l * 4 + sA) * 16384,
                      kqvb_l + ((size_t)sA * 3 + 0) * 128, K_A, NsA, 128, 0 };
            ds[3] = { feat_ptr(sA), WVMB + (size_t)rA * 16384, BVM + (size_t)rA * 128, VM_A, NsA, 128, 0 };
            ds[4] = { feat_ptr(sB), KWB + (size_t)(l * 4 + sB) * 16384,
                      kqvb_l + ((size_t)sB * 3 + 0) * 128, K_B, NsB, 128, 0 };
            ds[5] = { feat_ptr(sB), WVMB + (size_t)rB * 16384, BVM + (size_t)rB * 128, VM_B, NsB, 128, 0 };
            launch_batch(ds, 6);

            agg_dual<<<(Ndt + 3) / 4, 256, 0, stream>>>(
                QA_A, QA_B, K_A, VM_A, K_B, VM_B,
                RP + RPOFF[rA], RP + RPOFF[rB], SIDX,
                p_rel + (size_t)(l * 8 + rA) * 4, p_rel + (size_t)(l * 8 + rB) * 4,
                QA_A /*ACC alias*/, Ndt);

            size_t wi = (size_t)l * 4 + dt;
            const bfu* xr = feat_ptr(dt);
            bfu* ydst = (dt == 3) ? EVB :
                        (l == 0 ? LK0 : (l == 1 ? LK1 : L2F)) + (size_t)OFF[dt] * 128;
            mgemm_epi_layer<<<(Ndt + 63) / 64, 256, 0, stream>>>(
                QA_A, OWB + wi * 16384, out_b + wi * 128, xr, skip + wi,
                blk_ln_g + (size_t)l * 128, blk_ln_b + (size_t)l * 128, ydst, Ndt);
        }
    }

    // ---- fusion heads ----
    const int CH = 20000;
    for (int j = 0; j < 3; ++j) {
        int Nj = NT[j];
        for (int b0 = 0; b0 < Nj; b0 += CH) {
            int M = min(CH, Nj - b0);
            const bfu* srcs[3] = {
                LK0 + (size_t)(OFF[j] + b0) * 128,
                LK1 + (size_t)(OFF[j] + b0) * 128,
                L2F + (size_t)(OFF[j] + b0) * 128 };
            GDesc ds[9];
            int di = 0;
            for (int kk = 0; kk < 3; ++kk)
                for (int p = 0; p < 3; ++p) {
                    ds[di++] = { srcs[p], FINWB + (size_t)j * 49152 + (size_t)kk * 16384,
                                 fin_b + (size_t)j * 384 + kk * 128,
                                 QKVf + (size_t)(kk * 3 + p) * 128, M, 1152, 0 };
                }
            launch_batch(ds, 9);
            attn_fuse<<<(M + 3) / 4, 256, 0, stream>>>(QKVf, OMB, M);
            mgemm_epi_ln<<<(M + 63) / 64, 256, 0, stream>>>(
                OMB, FOUTWB + (size_t)j * 16384, fout_b + (size_t)j * 128,
                f_ln_g + (size_t)j * 128, f_ln_b + (size_t)j * 128,
                out + (size_t)(OFF[j] + b0) * 128, M);
        }
    }
}

// Round 11
// 1701.936 us; speedup vs baseline: 1.0589x; 1.0589x over previous
//
#include <hip/hip_runtime.h>
#include <math.h>

#define E_CNT 200000
typedef unsigned short bfu;
typedef unsigned short u16;
typedef __attribute__((ext_vector_type(8))) short bh8;
typedef __attribute__((ext_vector_type(4))) float f4;

__device__ __forceinline__ float gelu_f(float x) {
    return 0.5f * x * (1.0f + erff(x * 0.70710678118654752f));
}
__device__ __forceinline__ float bf2f(bfu u) { return __uint_as_float(((unsigned)u) << 16); }
__device__ __forceinline__ bfu f2bf(float f) {
    unsigned u = __float_as_uint(f);
    unsigned r = u + 0x7FFFu + ((u >> 16) & 1u);
    return (bfu)(r >> 16);
}
__device__ __forceinline__ int rsrc_of(int r) {
    const int a[8] = {0, 1, 2, 1, 3, 0, 3, 2}; return a[r];
}
__device__ __forceinline__ int rdst_of(int r) {
    const int a[8] = {1, 0, 1, 2, 0, 3, 2, 3}; return a[r];
}
__device__ __forceinline__ int rpoff_of(int r) {
    const int a[9] = {0, 20001, 50002, 70003, 95004, 125005, 175006, 200007, 250008};
    return a[r];
}

__global__ __launch_bounds__(256) void fill_val(float* p, int n, float v) {
    int i = blockIdx.x * 256 + threadIdx.x;
    if (i < n) p[i] = v;
}

// ---- one-shot f32->bf16 weight/emb converts ----
__global__ __launch_bounds__(256) void cvt_pack(
    const float* __restrict__ out_W, const float* __restrict__ kqv_W,
    const float* __restrict__ fin_W, const float* __restrict__ fout_W,
    const float* __restrict__ event_emb, const float* __restrict__ proj_W,
    bfu* __restrict__ OWB, bfu* __restrict__ KWB, bfu* __restrict__ FINWB,
    bfu* __restrict__ FOUTWB, bfu* __restrict__ EVB, bfu* __restrict__ PJWB)
{
    int i = blockIdx.x * 256 + threadIdx.x;
    const float* src; bfu* dst; size_t so, dox;
    if (i < 49152) { src = out_W; dst = OWB; so = (size_t)i * 4; dox = so; }
    else if (i < 98304) {
        int j = i - 49152; int m = j >> 12; int o = (j & 4095) * 4;
        src = kqv_W; dst = KWB;
        so = (size_t)m * 3 * 16384 + o; dox = (size_t)m * 16384 + o;
    }
    else if (i < 135168) { int j = i - 98304; src = fin_W; dst = FINWB; so = (size_t)j * 4; dox = so; }
    else if (i < 147456) { int j = i - 135168; src = fout_W; dst = FOUTWB; so = (size_t)j * 4; dox = so; }
    else if (i < 1747456) { int j = i - 147456; src = event_emb; dst = EVB; so = (size_t)j * 4; dox = so; }
    else if (i < 1753600) { int j = i - 1747456; src = proj_W; dst = PJWB; so = (size_t)j * 4; dox = so; }
    else return;
    float4 v = *(const float4*)(src + so);
    uint2 u;
    u.x = ((unsigned)f2bf(v.x)) | (((unsigned)f2bf(v.y)) << 16);
    u.y = ((unsigned)f2bf(v.z)) | (((unsigned)f2bf(v.w)) << 16);
    *(uint2*)(dst + dox) = u;
}

// ---- CSR build ----
__global__ __launch_bounds__(256) void hist_all(const int* __restrict__ edges, int* __restrict__ rp) {
    int i = blockIdx.x * 256 + threadIdx.x;
    if (i >= 8 * E_CNT) return;
    int r = i / E_CNT, e = i - r * E_CNT;
    int d = edges[(size_t)(2 * r + 1) * E_CNT + e];
    atomicAdd(&rp[rpoff_of(r) + d + 1], 1);
}
__global__ __launch_bounds__(1024) void scan_part(int* __restrict__ a, int* __restrict__ part, int n) {
    __shared__ int lds[1024];
    int t = threadIdx.x, i = blockIdx.x * 1024 + t;
    int v = (i < n) ? a[i] : 0;
    lds[t] = v;
    __syncthreads();
    for (int off = 1; off < 1024; off <<= 1) {
        int u = (t >= off) ? lds[t - off] : 0;
        __syncthreads();
        lds[t] += u;
        __syncthreads();
    }
    if (i < n) a[i] = lds[t];
    if (t == 1023) part[blockIdx.x] = lds[1023];
}
__global__ __launch_bounds__(256) void scan_tot(int* __restrict__ part, int nb) {
    __shared__ int lds[256];
    int t = threadIdx.x;
    int v = (t < nb) ? part[t] : 0;
    lds[t] = v;
    __syncthreads();
    for (int off = 1; off < 256; off <<= 1) {
        int u = (t >= off) ? lds[t - off] : 0;
        __syncthreads();
        lds[t] += u;
        __syncthreads();
    }
    if (t < nb) part[t] = lds[t];
}
__global__ __launch_bounds__(1024) void scan_add(int* __restrict__ a, const int* __restrict__ part, int n) {
    int b = blockIdx.x + 1;
    int i = b * 1024 + threadIdx.x;
    if (i < n) a[i] += part[b - 1];
}
__global__ __launch_bounds__(256) void scatter_all(
    const int* __restrict__ edges, const int* __restrict__ RP,
    int* __restrict__ cur, u16* __restrict__ SIDX) {
    int i = blockIdx.x * 256 + threadIdx.x;
    if (i >= 8 * E_CNT) return;
    int r = i / E_CNT, e = i - r * E_CNT;
    int d = edges[(size_t)(2 * r + 1) * E_CNT + e];
    int pos = RP[rpoff_of(r) + d] + atomicAdd(&cur[r * 50000 + d], 1);
    SIDX[pos] = (u16)edges[(size_t)(2 * r) * E_CNT + e];
}

// ---- MFMA input projection: f32[N,64] @ PJWB[128,64]^T + b, relu, bf16 out ----
struct PDesc { const float* X; const bfu* W; const float* bias; bfu* Y; int N; int bend; };
struct PBatch { PDesc d[3]; };

__global__ __launch_bounds__(256) void mgemm_proj(PBatch pb) {
    int b = blockIdx.x;
    int gi = 0;
    #pragma unroll
    for (int k = 0; k < 2; ++k) gi += (b >= pb.d[k].bend) ? 1 : 0;
    const float* X = pb.d[0].X; const bfu* W = pb.d[0].W;
    const float* bi = pb.d[0].bias; bfu* Y = pb.d[0].Y;
    int N = pb.d[0].N, bstart = 0;
    #pragma unroll
    for (int k = 1; k < 3; ++k) {
        if (gi == k) {
            X = pb.d[k].X; W = pb.d[k].W; bi = pb.d[k].bias; Y = pb.d[k].Y;
            N = pb.d[k].N; bstart = pb.d[k - 1].bend;
        }
    }
    int bloc = b - bstart;
    const int tid = threadIdx.x;
    const int wave = tid >> 6, lane = tid & 63;
    const int row16 = lane & 15, kgrp = lane >> 4;
    const int r_base = bloc * 128 + wave * 32;
    f4 acc[2][8];
    #pragma unroll
    for (int t = 0; t < 2; ++t)
        #pragma unroll
        for (int n = 0; n < 8; ++n) acc[t][n] = (f4){0.f, 0.f, 0.f, 0.f};
    bh8 az = {0, 0, 0, 0, 0, 0, 0, 0};
    #pragma unroll
    for (int kb = 0; kb < 2; ++kb) {
        bh8 a[2] = {az, az};
        #pragma unroll
        for (int t = 0; t < 2; ++t) {
            int ar = r_base + t * 16 + row16;
            if (ar < N) {
                const float* xp = X + (size_t)ar * 64 + kb * 32 + kgrp * 8;
                float4 xa = *(const float4*)xp;
                float4 xb = *(const float4*)(xp + 4);
                a[t][0] = (short)f2bf(xa.x); a[t][1] = (short)f2bf(xa.y);
                a[t][2] = (short)f2bf(xa.z); a[t][3] = (short)f2bf(xa.w);
                a[t][4] = (short)f2bf(xb.x); a[t][5] = (short)f2bf(xb.y);
                a[t][6] = (short)f2bf(xb.z); a[t][7] = (short)f2bf(xb.w);
            }
        }
        #pragma unroll
        for (int n = 0; n < 8; ++n) {
            bh8 bv = *(const bh8*)(W + (size_t)(n * 16 + row16) * 64 + kb * 32 + kgrp * 8);
            acc[0][n] = __builtin_amdgcn_mfma_f32_16x16x32_bf16(a[0], bv, acc[0][n], 0, 0, 0);
            acc[1][n] = __builtin_amdgcn_mfma_f32_16x16x32_bf16(a[1], bv, acc[1][n], 0, 0, 0);
        }
    }
    #pragma unroll
    for (int t = 0; t < 2; ++t) {
        const int crow0 = r_base + t * 16 + kgrp * 4;
        #pragma unroll
        for (int n = 0; n < 8; ++n) {
            int col = n * 16 + row16;
            float bn = bi[col];
            #pragma unroll
            for (int j = 0; j < 4; ++j) {
                int row = crow0 + j;
                if (row < N) Y[(size_t)row * 128 + col] = f2bf(fmaxf(acc[t][n][j] + bn, 0.f));
            }
        }
    }
}

// ---- merged relation-folded weight builder ----
__global__ __launch_bounds__(256) void build_rel(
    const float* __restrict__ kqvW_l, const float* __restrict__ kqvb_l,
    const float* __restrict__ a_l, const float* __restrict__ m_l,
    bfu* __restrict__ WQAB, float* __restrict__ BQA,
    bfu* __restrict__ WVMB, float* __restrict__ BVM)
{
    __shared__ float As[32][33];
    __shared__ float Ws[32][129];
    int tid = threadIdx.x;
    int b = blockIdx.x;
    if (b < 32) {
        int r = b >> 2, h = b & 3;
        int dt = rdst_of(r);
        const float* Wq = kqvW_l + ((size_t)dt * 3 + 1) * 16384;
        const float* bq = kqvb_l + ((size_t)dt * 3 + 1) * 128;
        const float* A = a_l + (size_t)r * 4096 + h * 1024;
        for (int v = tid; v < 1024; v += 256) As[v >> 5][v & 31] = A[v];
        for (int v = tid; v < 4096; v += 256)
            Ws[v >> 7][v & 127] = Wq[(size_t)(h * 32 + (v >> 7)) * 128 + (v & 127)];
        __syncthreads();
        int c = tid & 127, half = tid >> 7;
        for (int d = half; d < 32; d += 2) {
            float acc = 0.f;
            #pragma unroll
            for (int f = 0; f < 32; ++f) acc = fmaf(As[d][f], Ws[f][c], acc);
            WQAB[((size_t)r * 128 + h * 32 + d) * 128 + c] = f2bf(acc);
        }
        if (tid < 32) {
            int d = tid;
            float acc = 0.f;
            #pragma unroll
            for (int f = 0; f < 32; ++f) acc = fmaf(As[d][f], bq[h * 32 + f], acc);
            BQA[(size_t)r * 128 + h * 32 + d] = acc;
        }
    } else {
        int bb2 = b - 32;
        int r = bb2 >> 2, h = bb2 & 3;
        int st = rsrc_of(r);
        const float* Wv = kqvW_l + ((size_t)st * 3 + 2) * 16384;
        const float* bv = kqvb_l + ((size_t)st * 3 + 2) * 128;
        const float* M = m_l + (size_t)r * 4096 + h * 1024;
        for (int v = tid; v < 1024; v += 256) As[v >> 5][v & 31] = M[v];  // As holds M here
        for (int v = tid; v < 4096; v += 256)
            Ws[v >> 7][v & 127] = Wv[(size_t)(h * 32 + (v >> 7)) * 128 + (v & 127)];
        __syncthreads();
        int c = tid & 127, half = tid >> 7;
        for (int f = half; f < 32; f += 2) {
            float acc = 0.f;
            #pragma unroll
            for (int d = 0; d < 32; ++d) acc = fmaf(As[d][f], Ws[d][c], acc);
            WVMB[((size_t)r * 128 + h * 32 + f) * 128 + c] = f2bf(acc);
        }
        if (tid < 32) {
            int f = tid;
            float acc = 0.f;
            #pragma unroll
            for (int d = 0; d < 32; ++d) acc = fmaf(As[d][f], bv[h * 32 + d], acc);
            BVM[(size_t)r * 128 + h * 32 + f] = acc;
        }
    }
}

// ---- batched MFMA GEMM: up to 9 descriptors, 32 rows/wave, 128 rows/block ----
struct GDesc { const bfu* X; const bfu* W; const float* bias; bfu* Y; int N; int ldy; int bend; };
struct GBatch { GDesc d[9]; };

__global__ __launch_bounds__(256) void mgemm_batch(GBatch gb) {
    int b = blockIdx.x;
    int gi = 0;
    #pragma unroll
    for (int k = 0; k < 8; ++k) gi += (b >= gb.d[k].bend) ? 1 : 0;
    const bfu* X = gb.d[0].X; const bfu* W = gb.d[0].W;
    const float* bi = gb.d[0].bias; bfu* Y = gb.d[0].Y;
    int N = gb.d[0].N, ldy = gb.d[0].ldy, bstart = 0;
    #pragma unroll
    for (int k = 1; k < 9; ++k) {
        if (gi == k) {
            X = gb.d[k].X; W = gb.d[k].W; bi = gb.d[k].bias; Y = gb.d[k].Y;
            N = gb.d[k].N; ldy = gb.d[k].ldy; bstart = gb.d[k - 1].bend;
        }
    }
    int bloc = b - bstart;
    const int tid = threadIdx.x;
    const int wave = tid >> 6, lane = tid & 63;
    const int row16 = lane & 15, kgrp = lane >> 4;
    const int r_base = bloc * 128 + wave * 32;
    f4 acc[2][8];
    #pragma unroll
    for (int t = 0; t < 2; ++t)
        #pragma unroll
        for (int n = 0; n < 8; ++n) acc[t][n] = (f4){0.f, 0.f, 0.f, 0.f};
    bh8 az = {0, 0, 0, 0, 0, 0, 0, 0};
    #pragma unroll
    for (int kb = 0; kb < 4; ++kb) {
        int ar0 = r_base + row16, ar1 = r_base + 16 + row16;
        bh8 a0 = az, a1 = az;
        if (ar0 < N) a0 = *(const bh8*)(X + (size_t)ar0 * 128 + kb * 32 + kgrp * 8);
        if (ar1 < N) a1 = *(const bh8*)(X + (size_t)ar1 * 128 + kb * 32 + kgrp * 8);
        #pragma unroll
        for (int n = 0; n < 8; ++n) {
            bh8 bv = *(const bh8*)(W + (size_t)(n * 16 + row16) * 128 + kb * 32 + kgrp * 8);
            acc[0][n] = __builtin_amdgcn_mfma_f32_16x16x32_bf16(a0, bv, acc[0][n], 0, 0, 0);
            acc[1][n] = __builtin_amdgcn_mfma_f32_16x16x32_bf16(a1, bv, acc[1][n], 0, 0, 0);
        }
    }
    #pragma unroll
    for (int t = 0; t < 2; ++t) {
        const int crow0 = r_base + t * 16 + kgrp * 4;
        #pragma unroll
        for (int n = 0; n < 8; ++n) {
            int col = n * 16 + row16;
            float bn = bi[col];
            #pragma unroll
            for (int j = 0; j < 4; ++j) {
                int row = crow0 + j;
                if (row < N) Y[(size_t)row * ldy + col] = f2bf(acc[t][n][j] + bn);
            }
        }
    }
}

// ---- dual-relation flash aggregation: ONE wave per node, 4B loads, 4-edge unroll ----
// lane l: features c0=2l, c1=2l+1; head h = l>>4 (16-lane groups).
// Single online softmax chain across both relations. Output = gelu(a/d) bf16.
// ACC aliases QAA (row-owner-safe: wave reads its QAA row before writing it).
__global__ __launch_bounds__(256) void agg_dual(
    const bfu* QAA, const bfu* __restrict__ QAB,
    const bfu* __restrict__ KA, const bfu* __restrict__ VMA,
    const bfu* __restrict__ KB, const bfu* __restrict__ VMB,
    const int* __restrict__ rpA, const int* __restrict__ rpB,
    const u16* __restrict__ sidx,
    const float* __restrict__ prlA, const float* __restrict__ prlB,
    bfu* ACC, int Nn)
{
    int n = blockIdx.x * 4 + (threadIdx.x >> 6);
    if (n >= Nn) return;
    int l = threadIdx.x & 63;
    int h = l >> 4;
    const float scl = 0.17677669529663687f;

    float m = -3.0e38f, d = 0.f, a0 = 0.f, a1 = 0.f;

    auto upd = [&](float s, unsigned vu) {
        float nm = fmaxf(m, s);
        float sc = __expf(m - nm), w = __expf(s - nm);
        d = d * sc + w;
        a0 = fmaf(w, bf2f((bfu)vu), a0 * sc);
        a1 = fmaf(w, bf2f((bfu)(vu >> 16)), a1 * sc);
        m = nm;
    };

    auto rel = [&](const bfu* QA, const bfu* __restrict__ K, const bfu* __restrict__ VM,
                   const int* __restrict__ rp, const float* __restrict__ prl) {
        unsigned qu = *(const unsigned*)(QA + (size_t)n * 128 + 2 * l);
        float q0 = bf2f((bfu)qu), q1 = bf2f((bfu)(qu >> 16));
        float ph = prl[h] * scl;
        int i = rp[n], e1 = rp[n + 1];
        for (; i + 3 < e1; i += 4) {
            int sa = sidx[i], sb = sidx[i + 1], sc2 = sidx[i + 2], sd = sidx[i + 3];
            unsigned ka = *(const unsigned*)(K + (size_t)sa * 128 + 2 * l);
            unsigned kb = *(const unsigned*)(K + (size_t)sb * 128 + 2 * l);
            unsigned kc = *(const unsigned*)(K + (size_t)sc2 * 128 + 2 * l);
            unsigned kd = *(const unsigned*)(K + (size_t)sd * 128 + 2 * l);
            unsigned va = *(const unsigned*)(VM + (size_t)sa * 128 + 2 * l);
            unsigned vb = *(const unsigned*)(VM + (size_t)sb * 128 + 2 * l);
            unsigned vc = *(const unsigned*)(VM + (size_t)sc2 * 128 + 2 * l);
            unsigned vd = *(const unsigned*)(VM + (size_t)sd * 128 + 2 * l);
            float s0 = fmaf(bf2f((bfu)ka), q0, bf2f((bfu)(ka >> 16)) * q1);
            float s1 = fmaf(bf2f((bfu)kb), q0, bf2f((bfu)(kb >> 16)) * q1);
            float s2 = fmaf(bf2f((bfu)kc), q0, bf2f((bfu)(kc >> 16)) * q1);
            float s3 = fmaf(bf2f((bfu)kd), q0, bf2f((bfu)(kd >> 16)) * q1);
            #pragma unroll
            for (int off = 1; off <= 8; off <<= 1) {
                s0 += __shfl_xor(s0, off);
                s1 += __shfl_xor(s1, off);
                s2 += __shfl_xor(s2, off);
                s3 += __shfl_xor(s3, off);
            }
            upd(s0 * ph, va);
            upd(s1 * ph, vb);
            upd(s2 * ph, vc);
            upd(s3 * ph, vd);
        }
        for (; i < e1; ++i) {
            int sa = sidx[i];
            unsigned ka = *(const unsigned*)(K + (size_t)sa * 128 + 2 * l);
            unsigned va = *(const unsigned*)(VM + (size_t)sa * 128 + 2 * l);
            float s0 = fmaf(bf2f((bfu)ka), q0, bf2f((bfu)(ka >> 16)) * q1);
            #pragma unroll
            for (int off = 1; off <= 8; off <<= 1) s0 += __shfl_xor(s0, off);
            upd(s0 * ph, va);
        }
    };
    rel(QAA, KA, VMA, rpA, prlA);
    rel(QAB, KB, VMB, rpB, prlB);

    float rd = 1.f / fmaxf(d, 1e-16f);
    float y0 = gelu_f(a0 * rd);
    float y1 = gelu_f(a1 * rd);
    unsigned ou = ((unsigned)f2bf(y0)) | (((unsigned)f2bf(y1)) << 16);
    *(unsigned*)(ACC + (size_t)n * 128 + 2 * l) = ou;
}

// ---- layer epilogue: plain A (already gelu'd); out-proj; skip+LN+relu; bf16 out ----
__global__ __launch_bounds__(256) void mgemm_epi_layer(
    const bfu* __restrict__ A, const bfu* __restrict__ W, const float* __restrict__ bias,
    const bfu* __restrict__ Xr, const float* __restrict__ skp,
    const float* __restrict__ g, const float* __restrict__ bb,
    bfu* __restrict__ Y, int N)
{
    const int tid = threadIdx.x;
    const int wave = tid >> 6, lane = tid & 63;
    const int row16 = lane & 15, kgrp = lane >> 4;
    const int r_base = blockIdx.x * 64 + wave * 16;
    const int arow = r_base + row16;
    f4 acc[8];
    #pragma unroll
    for (int n = 0; n < 8; ++n) acc[n] = (f4){0.f, 0.f, 0.f, 0.f};
    bh8 az = {0, 0, 0, 0, 0, 0, 0, 0};
    #pragma unroll
    for (int kb = 0; kb < 4; ++kb) {
        bh8 a = az;
        if (arow < N) a = *(const bh8*)(A + (size_t)arow * 128 + kb * 32 + kgrp * 8);
        #pragma unroll
        for (int n = 0; n < 8; ++n) {
            bh8 bv = *(const bh8*)(W + (size_t)(n * 16 + row16) * 128 + kb * 32 + kgrp * 8);
            acc[n] = __builtin_amdgcn_mfma_f32_16x16x32_bf16(a, bv, acc[n], 0, 0, 0);
        }
    }
    const int crow0 = r_base + kgrp * 4;
    float sg = 1.f / (1.f + expf(-skp[0]));
    float z[8][4];
    #pragma unroll
    for (int n = 0; n < 8; ++n) {
        float bn = bias[n * 16 + row16];
        #pragma unroll
        for (int j = 0; j < 4; ++j) z[n][j] = acc[n][j] + bn;
    }
    #pragma unroll
    for (int j = 0; j < 4; ++j) {
        int row = crow0 + j;
        if (row >= N) continue;
        #pragma unroll
        for (int n = 0; n < 8; ++n) {
            float xr = bf2f(Xr[(size_t)row * 128 + n * 16 + row16]);
            z[n][j] = sg * z[n][j] + (1.f - sg) * xr + xr;
        }
    }
    float s[4], q[4];
    #pragma unroll
    for (int j = 0; j < 4; ++j) {
        s[j] = 0.f; q[j] = 0.f;
        #pragma unroll
        for (int n = 0; n < 8; ++n) { s[j] += z[n][j]; q[j] += z[n][j] * z[n][j]; }
    }
    #pragma unroll
    for (int off = 1; off <= 8; off <<= 1) {
        #pragma unroll
        for (int j = 0; j < 4; ++j) {
            s[j] += __shfl_xor(s[j], off);
            q[j] += __shfl_xor(q[j], off);
        }
    }
    #pragma unroll
    for (int j = 0; j < 4; ++j) {
        int row = crow0 + j;
        if (row >= N) continue;
        float mean = s[j] * (1.f / 128.f);
        float var = q[j] * (1.f / 128.f) - mean * mean;
        float inv = rsqrtf(var + 1e-5f);
        #pragma unroll
        for (int n = 0; n < 8; ++n) {
            int col = n * 16 + row16;
            float y = (z[n][j] - mean) * inv * g[col] + bb[col];
            Y[(size_t)row * 128 + col] = f2bf(fmaxf(y, 0.f));
        }
    }
}

// ---- fusion final: out-proj; LN; f32 out ----
__global__ __launch_bounds__(256) void mgemm_epi_ln(
    const bfu* __restrict__ X, const bfu* __restrict__ W, const float* __restrict__ bias,
    const float* __restrict__ g, const float* __restrict__ bb,
    float* __restrict__ Y, int N)
{
    const int tid = threadIdx.x;
    const int wave = tid >> 6, lane = tid & 63;
    const int row16 = lane & 15, kgrp = lane >> 4;
    const int r_base = blockIdx.x * 64 + wave * 16;
    const int arow = r_base + row16;
    f4 acc[8];
    #pragma unroll
    for (int n = 0; n < 8; ++n) acc[n] = (f4){0.f, 0.f, 0.f, 0.f};
    bh8 az = {0, 0, 0, 0, 0, 0, 0, 0};
    #pragma unroll
    for (int kb = 0; kb < 4; ++kb) {
        bh8 a = az;
        if (arow < N) a = *(const bh8*)(X + (size_t)arow * 128 + kb * 32 + kgrp * 8);
        #pragma unroll
        for (int n = 0; n < 8; ++n) {
            bh8 bv = *(const bh8*)(W + (size_t)(n * 16 + row16) * 128 + kb * 32 + kgrp * 8);
            acc[n] = __builtin_amdgcn_mfma_f32_16x16x32_bf16(a, bv, acc[n], 0, 0, 0);
        }
    }
    const int crow0 = r_base + kgrp * 4;
    float z[8][4];
    #pragma unroll
    for (int n = 0; n < 8; ++n) {
        float bn = bias[n * 16 + row16];
        #pragma unroll
        for (int j = 0; j < 4; ++j) z[n][j] = acc[n][j] + bn;
    }
    float s[4], q[4];
    #pragma unroll
    for (int j = 0; j < 4; ++j) {
        s[j] = 0.f; q[j] = 0.f;
        #pragma unroll
        for (int n = 0; n < 8; ++n) { s[j] += z[n][j]; q[j] += z[n][j] * z[n][j]; }
    }
    #pragma unroll
    for (int off = 1; off <= 8; off <<= 1) {
        #pragma unroll
        for (int j = 0; j < 4; ++j) {
            s[j] += __shfl_xor(s[j], off);
            q[j] += __shfl_xor(q[j], off);
        }
    }
    #pragma unroll
    for (int j = 0; j < 4; ++j) {
        int row = crow0 + j;
        if (row >= N) continue;
        float mean = s[j] * (1.f / 128.f);
        float var = q[j] * (1.f / 128.f) - mean * mean;
        float inv = rsqrtf(var + 1e-5f);
        #pragma unroll
        for (int n = 0; n < 8; ++n) {
            int col = n * 16 + row16;
            Y[(size_t)row * 128 + col] = (z[n][j] - mean) * inv * g[col] + bb[col];
        }
    }
}

// ---- fusion attention (3 tokens, 4 heads), wave per node, bf16 out ----
__global__ __launch_bounds__(256) void attn_fuse(
    const bfu* __restrict__ QKV, bfu* __restrict__ OM, int M)
{
    int n = blockIdx.x * 4 + (threadIdx.x >> 6);
    int l = threadIdx.x & 63;
    if (n >= M) return;
    const bfu* base = QKV + (size_t)n * 1152;
    float q[3][2], k[3][2], v[3][2];
    #pragma unroll
    for (int p = 0; p < 3; ++p) {
        q[p][0] = bf2f(base[(0 * 3 + p) * 128 + l]);
        q[p][1] = bf2f(base[(0 * 3 + p) * 128 + l + 64]);
        k[p][0] = bf2f(base[(1 * 3 + p) * 128 + l]);
        k[p][1] = bf2f(base[(1 * 3 + p) * 128 + l + 64]);
        v[p][0] = bf2f(base[(2 * 3 + p) * 128 + l]);
        v[p][1] = bf2f(base[(2 * 3 + p) * 128 + l + 64]);
    }
    float lgA[3][3], lgB[3][3];
    #pragma unroll
    for (int qi = 0; qi < 3; ++qi)
        #pragma unroll
        for (int ki = 0; ki < 3; ++ki) {
            float s0 = q[qi][0] * k[ki][0];
            float s1 = q[qi][1] * k[ki][1];
            #pragma unroll
            for (int off = 1; off <= 16; off <<= 1) {
                s0 += __shfl_xor(s0, off);
                s1 += __shfl_xor(s1, off);
            }
            lgA[qi][ki] = s0 * 0.17677669529663687f;
            lgB[qi][ki] = s1 * 0.17677669529663687f;
        }
    float oA = 0.f, oB = 0.f;
    #pragma unroll
    for (int qi = 0; qi < 3; ++qi) {
        float mA = fmaxf(lgA[qi][0], fmaxf(lgA[qi][1], lgA[qi][2]));
        float e0 = __expf(lgA[qi][0] - mA), e1 = __expf(lgA[qi][1] - mA), e2 = __expf(lgA[qi][2] - mA);
        float rd = 1.f / (e0 + e1 + e2);
        oA += (e0 * v[0][0] + e1 * v[1][0] + e2 * v[2][0]) * rd;
        float mB = fmaxf(lgB[qi][0], fmaxf(lgB[qi][1], lgB[qi][2]));
        float f0 = __expf(lgB[qi][0] - mB), f1 = __expf(lgB[qi][1] - mB), f2 = __expf(lgB[qi][2] - mB);
        float rdB = 1.f / (f0 + f1 + f2);
        oB += (f0 * v[0][1] + f1 * v[1][1] + f2 * v[2][1]) * rdB;
    }
    OM[(size_t)n * 128 + l] = f2bf(oA * (1.f / 3.f));
    OM[(size_t)n * 128 + l + 64] = f2bf(oB * (1.f / 3.f));
}

extern "C" void kernel_launch(void* const* d_in, const int* in_sizes, int n_in,
                              void* d_out, int out_size, void* d_ws, size_t ws_size,
                              hipStream_t stream)
{
    const float* x_pest   = (const float*)d_in[0];
    const float* x_dis    = (const float*)d_in[1];
    const float* x_plant  = (const float*)d_in[2];
    const int*   edges    = (const int*)d_in[3];
    const float* proj_W   = (const float*)d_in[4];
    const float* proj_b   = (const float*)d_in[5];
    const float* event_emb= (const float*)d_in[6];
    const float* kqv_W    = (const float*)d_in[7];
    const float* kqv_b    = (const float*)d_in[8];
    const float* out_W    = (const float*)d_in[9];
    const float* out_b    = (const float*)d_in[10];
    const float* skip     = (const float*)d_in[11];
    const float* a_rel    = (const float*)d_in[12];
    const float* m_rel    = (const float*)d_in[13];
    const float* p_rel    = (const float*)d_in[14];
    const float* blk_ln_g = (const float*)d_in[15];
    const float* blk_ln_b = (const float*)d_in[16];
    const float* fin_W    = (const float*)d_in[17];
    const float* fin_b    = (const float*)d_in[18];
    const float* fout_W   = (const float*)d_in[19];
    const float* fout_b   = (const float*)d_in[20];
    const float* f_ln_g   = (const float*)d_in[21];
    const float* f_ln_b   = (const float*)d_in[22];
    float* out = (float*)d_out;

    static const int NT[4]  = {30000, 20000, 25000, 50000};
    static const int OFF[4] = {0, 30000, 50000, 75000};
    static const int RPOFF[9] = {0, 20001, 50002, 70003, 95004, 125005, 175006, 200007, 250008};
    static const int DG[4][2][2] = { {{1,1},{4,3}}, {{0,0},{2,2}}, {{3,1},{6,3}}, {{5,0},{7,2}} };

    char* wsb = (char*)d_ws;
    size_t ob = 0;
    auto alc = [&](size_t bytes) -> void* {
        void* p = wsb + ob; ob += (bytes + 255) & ~(size_t)255; return p;
    };
    bfu* LK0  = (bfu*)alc((size_t)75000 * 128 * 2);
    bfu* LK1  = (bfu*)alc((size_t)75000 * 128 * 2);
    bfu* POOL = (bfu*)alc((size_t)210000 * 128 * 2);   // QA_A/QA_B/K/VM pool; fusion QKV; CUR
    bfu* WQAB = (bfu*)alc((size_t)8 * 16384 * 2);
    float* BQA = (float*)alc((size_t)8 * 128 * 4);
    bfu* WVMB = (bfu*)alc((size_t)8 * 16384 * 2);
    float* BVM = (float*)alc((size_t)8 * 128 * 4);
    bfu* KWB  = (bfu*)alc((size_t)12 * 16384 * 2);
    bfu* OWB  = (bfu*)alc((size_t)12 * 16384 * 2);
    bfu* FINWB = (bfu*)alc((size_t)3 * 49152 * 2);
    bfu* FOUTWB = (bfu*)alc((size_t)3 * 16384 * 2);
    bfu* PJWB = (bfu*)alc((size_t)3 * 8192 * 2);
    int* RP   = (int*)alc((size_t)250008 * 4);
    int* PART = (int*)alc(1024);
    u16* SIDX = (u16*)alc((size_t)8 * E_CNT * 2);
    if (ws_size < ob) {
        fill_val<<<(out_size + 255) / 256, 256, 0, stream>>>(out, out_size, 1e30f);
        return;
    }
    int* CUR = (int*)POOL;       // CSR counters (1.6MB), used before pool
    bfu* QKVf = POOL;            // fusion QKV (CH*1152*2 <= 46.08MB <= 53.76MB)
    bfu* OMB  = POOL + (size_t)20000 * 1152;  // attn out (5.12MB, ends at 51.2MB)

    // d_out overlay (time-disjoint): EVB [0,12.8M); XB [12.8,32.0M); L2F [19.2,38.4M)
    bfu* EVB = (bfu*)out;
    bfu* XB  = (bfu*)((char*)out + 12800000);
    bfu* L2F = (bfu*)((char*)out + 19200000);

    cvt_pack<<<(1753600 + 255) / 256, 256, 0, stream>>>(
        out_W, kqv_W, fin_W, fout_W, event_emb, proj_W,
        OWB, KWB, FINWB, FOUTWB, EVB, PJWB);

    // ---- CSR build ----
    hipMemsetAsync(RP, 0, (size_t)250008 * 4, stream);
    const int eg8 = (8 * E_CNT + 255) / 256;
    hist_all<<<eg8, 256, 0, stream>>>(edges, RP);
    scan_part<<<245, 1024, 0, stream>>>(RP, PART, 250008);
    scan_tot<<<1, 256, 0, stream>>>(PART, 245);
    scan_add<<<244, 1024, 0, stream>>>(RP, PART, 250008);
    hipMemsetAsync(CUR, 0, (size_t)8 * 50000 * 4, stream);
    scatter_all<<<eg8, 256, 0, stream>>>(edges, RP, CUR, SIDX);

    // ---- input projections (one MFMA batch launch) ----
    {
        PBatch pb;
        const float* xin0[3] = {x_pest, x_dis, x_plant};
        int acc = 0;
        for (int t = 0; t < 3; ++t) {
            pb.d[t].X = xin0[t];
            pb.d[t].W = PJWB + (size_t)t * 8192;
            pb.d[t].bias = proj_b + (size_t)t * 128;
            pb.d[t].Y = XB + (size_t)OFF[t] * 128;
            pb.d[t].N = NT[t];
            acc += (NT[t] + 127) / 128;
            pb.d[t].bend = acc;
        }
        mgemm_proj<<<acc, 256, 0, stream>>>(pb);
    }

    auto launch_batch = [&](GDesc* ds, int cnt) {
        GBatch gb;
        int acc = 0;
        for (int i = 0; i < cnt; ++i) {
            gb.d[i] = ds[i];
            acc += (ds[i].N + 127) / 128;
            gb.d[i].bend = acc;
        }
        for (int i = cnt; i < 9; ++i) { gb.d[i] = gb.d[cnt - 1]; gb.d[i].bend = acc; }
        mgemm_batch<<<acc, 256, 0, stream>>>(gb);
    };

    for (int l = 0; l < 3; ++l) {
        const float* kqvW_l = kqv_W + (size_t)l * 12 * 16384;
        const float* kqvb_l = kqv_b + (size_t)l * 12 * 128;
        build_rel<<<64, 256, 0, stream>>>(kqvW_l, kqvb_l,
            a_rel + (size_t)l * 8 * 4096, m_rel + (size_t)l * 8 * 4096,
            WQAB, BQA, WVMB, BVM);

        auto feat_ptr = [&](int tt) -> const bfu* {
            if (tt == 3) return EVB;
            if (l == 0) return XB + (size_t)OFF[tt] * 128;
            return (l == 1 ? LK0 : LK1) + (size_t)OFF[tt] * 128;
        };

        int nord = (l == 2) ? 3 : 4;
        for (int dt = 0; dt < nord; ++dt) {
            int Ndt = NT[dt];
            int rA = DG[dt][0][0], sA = DG[dt][0][1];
            int rB = DG[dt][1][0], sB = DG[dt][1][1];
            int NsA = NT[sA], NsB = NT[sB];
            // pool layout (rows of 128 bf16): QA_A | QA_B | K_A | VM_A | K_B | VM_B
            bfu* QA_A = POOL;
            bfu* QA_B = QA_A + (size_t)Ndt * 128;
            bfu* K_A  = QA_B + (size_t)Ndt * 128;
            bfu* VM_A = K_A + (size_t)NsA * 128;
            bfu* K_B  = VM_A + (size_t)NsA * 128;
            bfu* VM_B = K_B + (size_t)NsB * 128;

            GDesc ds[6];
            ds[0] = { feat_ptr(dt), WQAB + (size_t)rA * 16384, BQA + (size_t)rA * 128, QA_A, Ndt, 128, 0 };
            ds[1] = { feat_ptr(dt), WQAB + (size_t)rB * 16384, BQA + (size_t)rB * 128, QA_B, Ndt, 128, 0 };
            ds[2] = { feat_ptr(sA), KWB + (size_t)(l * 4 + sA) * 16384,
                      kqvb_l + ((size_t)sA * 3 + 0) * 128, K_A, NsA, 128, 0 };
            ds[3] = { feat_ptr(sA), WVMB + (size_t)rA * 16384, BVM + (size_t)rA * 128, VM_A, NsA, 128, 0 };
            ds[4] = { feat_ptr(sB), KWB + (size_t)(l * 4 + sB) * 16384,
                      kqvb_l + ((size_t)sB * 3 + 0) * 128, K_B, NsB, 128, 0 };
            ds[5] = { feat_ptr(sB), WVMB + (size_t)rB * 16384, BVM + (size_t)rB * 128, VM_B, NsB, 128, 0 };
            launch_batch(ds, 6);

            agg_dual<<<(Ndt + 3) / 4, 256, 0, stream>>>(
                QA_A, QA_B, K_A, VM_A, K_B, VM_B,
                RP + RPOFF[rA], RP + RPOFF[rB], SIDX,
                p_rel + (size_t)(l * 8 + rA) * 4, p_rel + (size_t)(l * 8 + rB) * 4,
                QA_A /*ACC alias*/, Ndt);

            size_t wi = (size_t)l * 4 + dt;
            const bfu* xr = feat_ptr(dt);
            bfu* ydst = (dt == 3) ? EVB :
                        (l == 0 ? LK0 : (l == 1 ? LK1 : L2F)) + (size_t)OFF[dt] * 128;
            mgemm_epi_layer<<<(Ndt + 63) / 64, 256, 0, stream>>>(
                QA_A, OWB + wi * 16384, out_b + wi * 128, xr, skip + wi,
                blk_ln_g + (size_t)l * 128, blk_ln_b + (size_t)l * 128, ydst, Ndt);
        }
    }

    // ---- fusion heads ----
    const int CH = 20000;
    for (int j = 0; j < 3; ++j) {
        int Nj = NT[j];
        for (int b0 = 0; b0 < Nj; b0 += CH) {
            int M = min(CH, Nj - b0);
            const bfu* srcs[3] = {
                LK0 + (size_t)(OFF[j] + b0) * 128,
                LK1 + (size_t)(OFF[j] + b0) * 128,
                L2F + (size_t)(OFF[j] + b0) * 128 };
            GDesc ds[9];
            int di = 0;
            for (int kk = 0; kk < 3; ++kk)
                for (int p = 0; p < 3; ++p) {
                    ds[di++] = { srcs[p], FINWB + (size_t)j * 49152 + (size_t)kk * 16384,
                                 fin_b + (size_t)j * 384 + kk * 128,
                                 QKVf + (size_t)(kk * 3 + p) * 128, M, 1152, 0 };
                }
            launch_batch(ds, 9);
            attn_fuse<<<(M + 3) / 4, 256, 0, stream>>>(QKVf, OMB, M);
            mgemm_epi_ln<<<(M + 63) / 64, 256, 0, stream>>>(
                OMB, FOUTWB + (size_t)j * 16384, fout_b + (size_t)j * 128,
                f_ln_g + (size_t)j * 128, f_ln_b + (size_t)j * 128,
                out + (size_t)(OFF[j] + b0) * 128, M);
        }
    }
}

// Round 12
// 1696.969 us; speedup vs baseline: 1.0620x; 1.0029x over previous
//
#include <hip/hip_runtime.h>
#include <math.h>

#define E_CNT 200000
typedef unsigned short bfu;
typedef unsigned short u16;
typedef __attribute__((ext_vector_type(8))) short bh8;
typedef __attribute__((ext_vector_type(4))) float f4;

__device__ __forceinline__ float gelu_f(float x) {
    return 0.5f * x * (1.0f + erff(x * 0.70710678118654752f));
}
__device__ __forceinline__ float bf2f(bfu u) { return __uint_as_float(((unsigned)u) << 16); }
__device__ __forceinline__ bfu f2bf(float f) {
    unsigned u = __float_as_uint(f);
    unsigned r = u + 0x7FFFu + ((u >> 16) & 1u);
    return (bfu)(r >> 16);
}
__device__ __forceinline__ int rsrc_of(int r) {
    const int a[8] = {0, 1, 2, 1, 3, 0, 3, 2}; return a[r];
}
__device__ __forceinline__ int rdst_of(int r) {
    const int a[8] = {1, 0, 1, 2, 0, 3, 2, 3}; return a[r];
}
__device__ __forceinline__ int rpoff_of(int r) {
    const int a[9] = {0, 20001, 50002, 70003, 95004, 125005, 175006, 200007, 250008};
    return a[r];
}

__global__ __launch_bounds__(256) void fill_val(float* p, int n, float v) {
    int i = blockIdx.x * 256 + threadIdx.x;
    if (i < n) p[i] = v;
}

// ---- one-shot f32->bf16 weight/emb converts ----
__global__ __launch_bounds__(256) void cvt_pack(
    const float* __restrict__ out_W, const float* __restrict__ kqv_W,
    const float* __restrict__ fin_W, const float* __restrict__ fout_W,
    const float* __restrict__ event_emb, const float* __restrict__ proj_W,
    bfu* __restrict__ OWB, bfu* __restrict__ KWB, bfu* __restrict__ FINWB,
    bfu* __restrict__ FOUTWB, bfu* __restrict__ EVB, bfu* __restrict__ PJWB)
{
    int i = blockIdx.x * 256 + threadIdx.x;
    const float* src; bfu* dst; size_t so, dox;
    if (i < 49152) { src = out_W; dst = OWB; so = (size_t)i * 4; dox = so; }
    else if (i < 98304) {
        int j = i - 49152; int m = j >> 12; int o = (j & 4095) * 4;
        src = kqv_W; dst = KWB;
        so = (size_t)m * 3 * 16384 + o; dox = (size_t)m * 16384 + o;
    }
    else if (i < 135168) { int j = i - 98304; src = fin_W; dst = FINWB; so = (size_t)j * 4; dox = so; }
    else if (i < 147456) { int j = i - 135168; src = fout_W; dst = FOUTWB; so = (size_t)j * 4; dox = so; }
    else if (i < 1747456) { int j = i - 147456; src = event_emb; dst = EVB; so = (size_t)j * 4; dox = so; }
    else if (i < 1753600) { int j = i - 1747456; src = proj_W; dst = PJWB; so = (size_t)j * 4; dox = so; }
    else return;
    float4 v = *(const float4*)(src + so);
    uint2 u;
    u.x = ((unsigned)f2bf(v.x)) | (((unsigned)f2bf(v.y)) << 16);
    u.y = ((unsigned)f2bf(v.z)) | (((unsigned)f2bf(v.w)) << 16);
    *(uint2*)(dst + dox) = u;
}

// ---- CSR build ----
__global__ __launch_bounds__(256) void hist_all(const int* __restrict__ edges, int* __restrict__ rp) {
    int i = blockIdx.x * 256 + threadIdx.x;
    if (i >= 8 * E_CNT) return;
    int r = i / E_CNT, e = i - r * E_CNT;
    int d = edges[(size_t)(2 * r + 1) * E_CNT + e];
    atomicAdd(&rp[rpoff_of(r) + d + 1], 1);
}
__global__ __launch_bounds__(1024) void scan_part(int* __restrict__ a, int* __restrict__ part, int n) {
    __shared__ int lds[1024];
    int t = threadIdx.x, i = blockIdx.x * 1024 + t;
    int v = (i < n) ? a[i] : 0;
    lds[t] = v;
    __syncthreads();
    for (int off = 1; off < 1024; off <<= 1) {
        int u = (t >= off) ? lds[t - off] : 0;
        __syncthreads();
        lds[t] += u;
        __syncthreads();
    }
    if (i < n) a[i] = lds[t];
    if (t == 1023) part[blockIdx.x] = lds[1023];
}
__global__ __launch_bounds__(256) void scan_tot(int* __restrict__ part, int nb) {
    __shared__ int lds[256];
    int t = threadIdx.x;
    int v = (t < nb) ? part[t] : 0;
    lds[t] = v;
    __syncthreads();
    for (int off = 1; off < 256; off <<= 1) {
        int u = (t >= off) ? lds[t - off] : 0;
        __syncthreads();
        lds[t] += u;
        __syncthreads();
    }
    if (t < nb) part[t] = lds[t];
}
__global__ __launch_bounds__(1024) void scan_add(int* __restrict__ a, const int* __restrict__ part, int n) {
    int b = blockIdx.x + 1;
    int i = b * 1024 + threadIdx.x;
    if (i < n) a[i] += part[b - 1];
}
__global__ __launch_bounds__(256) void scatter_all(
    const int* __restrict__ edges, const int* __restrict__ RP,
    int* __restrict__ cur, u16* __restrict__ SIDX) {
    int i = blockIdx.x * 256 + threadIdx.x;
    if (i >= 8 * E_CNT) return;
    int r = i / E_CNT, e = i - r * E_CNT;
    int d = edges[(size_t)(2 * r + 1) * E_CNT + e];
    int pos = RP[rpoff_of(r) + d] + atomicAdd(&cur[r * 50000 + d], 1);
    SIDX[pos] = (u16)edges[(size_t)(2 * r) * E_CNT + e];
}

// ---- MFMA input projection: f32[N,64] @ PJWB[128,64]^T + b, relu, bf16 out ----
struct PDesc { const float* X; const bfu* W; const float* bias; bfu* Y; int N; int bend; };
struct PBatch { PDesc d[3]; };

__global__ __launch_bounds__(256) void mgemm_proj(PBatch pb) {
    int b = blockIdx.x;
    int gi = 0;
    #pragma unroll
    for (int k = 0; k < 2; ++k) gi += (b >= pb.d[k].bend) ? 1 : 0;
    const float* X = pb.d[0].X; const bfu* W = pb.d[0].W;
    const float* bi = pb.d[0].bias; bfu* Y = pb.d[0].Y;
    int N = pb.d[0].N, bstart = 0;
    #pragma unroll
    for (int k = 1; k < 3; ++k) {
        if (gi == k) {
            X = pb.d[k].X; W = pb.d[k].W; bi = pb.d[k].bias; Y = pb.d[k].Y;
            N = pb.d[k].N; bstart = pb.d[k - 1].bend;
        }
    }
    int bloc = b - bstart;
    const int tid = threadIdx.x;
    const int wave = tid >> 6, lane = tid & 63;
    const int row16 = lane & 15, kgrp = lane >> 4;
    const int r_base = bloc * 128 + wave * 32;
    f4 acc[2][8];
    #pragma unroll
    for (int t = 0; t < 2; ++t)
        #pragma unroll
        for (int n = 0; n < 8; ++n) acc[t][n] = (f4){0.f, 0.f, 0.f, 0.f};
    bh8 az = {0, 0, 0, 0, 0, 0, 0, 0};
    #pragma unroll
    for (int kb = 0; kb < 2; ++kb) {
        bh8 a[2] = {az, az};
        #pragma unroll
        for (int t = 0; t < 2; ++t) {
            int ar = r_base + t * 16 + row16;
            if (ar < N) {
                const float* xp = X + (size_t)ar * 64 + kb * 32 + kgrp * 8;
                float4 xa = *(const float4*)xp;
                float4 xb = *(const float4*)(xp + 4);
                a[t][0] = (short)f2bf(xa.x); a[t][1] = (short)f2bf(xa.y);
                a[t][2] = (short)f2bf(xa.z); a[t][3] = (short)f2bf(xa.w);
                a[t][4] = (short)f2bf(xb.x); a[t][5] = (short)f2bf(xb.y);
                a[t][6] = (short)f2bf(xb.z); a[t][7] = (short)f2bf(xb.w);
            }
        }
        #pragma unroll
        for (int n = 0; n < 8; ++n) {
            bh8 bv = *(const bh8*)(W + (size_t)(n * 16 + row16) * 64 + kb * 32 + kgrp * 8);
            acc[0][n] = __builtin_amdgcn_mfma_f32_16x16x32_bf16(a[0], bv, acc[0][n], 0, 0, 0);
            acc[1][n] = __builtin_amdgcn_mfma_f32_16x16x32_bf16(a[1], bv, acc[1][n], 0, 0, 0);
        }
    }
    #pragma unroll
    for (int t = 0; t < 2; ++t) {
        const int crow0 = r_base + t * 16 + kgrp * 4;
        #pragma unroll
        for (int n = 0; n < 8; ++n) {
            int col = n * 16 + row16;
            float bn = bi[col];
            #pragma unroll
            for (int j = 0; j < 4; ++j) {
                int row = crow0 + j;
                if (row < N) Y[(size_t)row * 128 + col] = f2bf(fmaxf(acc[t][n][j] + bn, 0.f));
            }
        }
    }
}

// ---- merged relation-folded weight builder ----
__global__ __launch_bounds__(256) void build_rel(
    const float* __restrict__ kqvW_l, const float* __restrict__ kqvb_l,
    const float* __restrict__ a_l, const float* __restrict__ m_l,
    bfu* __restrict__ WQAB, float* __restrict__ BQA,
    bfu* __restrict__ WVMB, float* __restrict__ BVM)
{
    __shared__ float As[32][33];
    __shared__ float Ws[32][129];
    int tid = threadIdx.x;
    int b = blockIdx.x;
    if (b < 32) {
        int r = b >> 2, h = b & 3;
        int dt = rdst_of(r);
        const float* Wq = kqvW_l + ((size_t)dt * 3 + 1) * 16384;
        const float* bq = kqvb_l + ((size_t)dt * 3 + 1) * 128;
        const float* A = a_l + (size_t)r * 4096 + h * 1024;
        for (int v = tid; v < 1024; v += 256) As[v >> 5][v & 31] = A[v];
        for (int v = tid; v < 4096; v += 256)
            Ws[v >> 7][v & 127] = Wq[(size_t)(h * 32 + (v >> 7)) * 128 + (v & 127)];
        __syncthreads();
        int c = tid & 127, half = tid >> 7;
        for (int d = half; d < 32; d += 2) {
            float acc = 0.f;
            #pragma unroll
            for (int f = 0; f < 32; ++f) acc = fmaf(As[d][f], Ws[f][c], acc);
            WQAB[((size_t)r * 128 + h * 32 + d) * 128 + c] = f2bf(acc);
        }
        if (tid < 32) {
            int d = tid;
            float acc = 0.f;
            #pragma unroll
            for (int f = 0; f < 32; ++f) acc = fmaf(As[d][f], bq[h * 32 + f], acc);
            BQA[(size_t)r * 128 + h * 32 + d] = acc;
        }
    } else {
        int bb2 = b - 32;
        int r = bb2 >> 2, h = bb2 & 3;
        int st = rsrc_of(r);
        const float* Wv = kqvW_l + ((size_t)st * 3 + 2) * 16384;
        const float* bv = kqvb_l + ((size_t)st * 3 + 2) * 128;
        const float* M = m_l + (size_t)r * 4096 + h * 1024;
        for (int v = tid; v < 1024; v += 256) As[v >> 5][v & 31] = M[v];  // As holds M here
        for (int v = tid; v < 4096; v += 256)
            Ws[v >> 7][v & 127] = Wv[(size_t)(h * 32 + (v >> 7)) * 128 + (v & 127)];
        __syncthreads();
        int c = tid & 127, half = tid >> 7;
        for (int f = half; f < 32; f += 2) {
            float acc = 0.f;
            #pragma unroll
            for (int d = 0; d < 32; ++d) acc = fmaf(As[d][f], Ws[d][c], acc);
            WVMB[((size_t)r * 128 + h * 32 + f) * 128 + c] = f2bf(acc);
        }
        if (tid < 32) {
            int f = tid;
            float acc = 0.f;
            #pragma unroll
            for (int d = 0; d < 32; ++d) acc = fmaf(As[d][f], bv[h * 32 + d], acc);
            BVM[(size_t)r * 128 + h * 32 + f] = acc;
        }
    }
}

// ---- batched MFMA GEMM: up to 9 descriptors, 32 rows/wave, 128 rows/block ----
struct GDesc { const bfu* X; const bfu* W; const float* bias; bfu* Y; int N; int ldy; int bend; };
struct GBatch { GDesc d[9]; };

__global__ __launch_bounds__(256) void mgemm_batch(GBatch gb) {
    int b = blockIdx.x;
    int gi = 0;
    #pragma unroll
    for (int k = 0; k < 8; ++k) gi += (b >= gb.d[k].bend) ? 1 : 0;
    const bfu* X = gb.d[0].X; const bfu* W = gb.d[0].W;
    const float* bi = gb.d[0].bias; bfu* Y = gb.d[0].Y;
    int N = gb.d[0].N, ldy = gb.d[0].ldy, bstart = 0;
    #pragma unroll
    for (int k = 1; k < 9; ++k) {
        if (gi == k) {
            X = gb.d[k].X; W = gb.d[k].W; bi = gb.d[k].bias; Y = gb.d[k].Y;
            N = gb.d[k].N; ldy = gb.d[k].ldy; bstart = gb.d[k - 1].bend;
        }
    }
    int bloc = b - bstart;
    const int tid = threadIdx.x;
    const int wave = tid >> 6, lane = tid & 63;
    const int row16 = lane & 15, kgrp = lane >> 4;
    const int r_base = bloc * 128 + wave * 32;
    f4 acc[2][8];
    #pragma unroll
    for (int t = 0; t < 2; ++t)
        #pragma unroll
        for (int n = 0; n < 8; ++n) acc[t][n] = (f4){0.f, 0.f, 0.f, 0.f};
    bh8 az = {0, 0, 0, 0, 0, 0, 0, 0};
    #pragma unroll
    for (int kb = 0; kb < 4; ++kb) {
        int ar0 = r_base + row16, ar1 = r_base + 16 + row16;
        bh8 a0 = az, a1 = az;
        if (ar0 < N) a0 = *(const bh8*)(X + (size_t)ar0 * 128 + kb * 32 + kgrp * 8);
        if (ar1 < N) a1 = *(const bh8*)(X + (size_t)ar1 * 128 + kb * 32 + kgrp * 8);
        #pragma unroll
        for (int n = 0; n < 8; ++n) {
            bh8 bv = *(const bh8*)(W + (size_t)(n * 16 + row16) * 128 + kb * 32 + kgrp * 8);
            acc[0][n] = __builtin_amdgcn_mfma_f32_16x16x32_bf16(a0, bv, acc[0][n], 0, 0, 0);
            acc[1][n] = __builtin_amdgcn_mfma_f32_16x16x32_bf16(a1, bv, acc[1][n], 0, 0, 0);
        }
    }
    #pragma unroll
    for (int t = 0; t < 2; ++t) {
        const int crow0 = r_base + t * 16 + kgrp * 4;
        #pragma unroll
        for (int n = 0; n < 8; ++n) {
            int col = n * 16 + row16;
            float bn = bi[col];
            #pragma unroll
            for (int j = 0; j < 4; ++j) {
                int row = crow0 + j;
                if (row < N) Y[(size_t)row * ldy + col] = f2bf(acc[t][n][j] + bn);
            }
        }
    }
}

// ---- dual-relation flash aggregation with interleaved KV rows ----
// KV[s] = 256 bf16: [K row 128 | VM row 128] -> one edge = one contiguous 512B gather.
// Two independent online-softmax chains (even/odd edges), merged once at end.
// lane l: features c0=2l, c1=2l+1; head h = l>>4. Output = gelu(a/d) bf16.
// ACC aliases QAA (row-owner-safe).
__global__ __launch_bounds__(256) void agg_dual(
    const bfu* QAA, const bfu* __restrict__ QAB,
    const bfu* __restrict__ KVA, const bfu* __restrict__ KVB,
    const int* __restrict__ rpA, const int* __restrict__ rpB,
    const u16* __restrict__ sidx,
    const float* __restrict__ prlA, const float* __restrict__ prlB,
    bfu* ACC, int Nn)
{
    int n = blockIdx.x * 4 + (threadIdx.x >> 6);
    if (n >= Nn) return;
    int l = threadIdx.x & 63;
    int h = l >> 4;
    const float scl = 0.17677669529663687f;

    float m0 = -3.0e38f, d0 = 0.f, x0 = 0.f, y0 = 0.f;  // chain 0
    float m1 = -3.0e38f, d1 = 0.f, x1 = 0.f, y1 = 0.f;  // chain 1

    auto upd0 = [&](float s, unsigned vu) {
        float nm = fmaxf(m0, s);
        float sc = __expf(m0 - nm), w = __expf(s - nm);
        d0 = d0 * sc + w;
        x0 = fmaf(w, bf2f((bfu)vu), x0 * sc);
        y0 = fmaf(w, bf2f((bfu)(vu >> 16)), y0 * sc);
        m0 = nm;
    };
    auto upd1 = [&](float s, unsigned vu) {
        float nm = fmaxf(m1, s);
        float sc = __expf(m1 - nm), w = __expf(s - nm);
        d1 = d1 * sc + w;
        x1 = fmaf(w, bf2f((bfu)vu), x1 * sc);
        y1 = fmaf(w, bf2f((bfu)(vu >> 16)), y1 * sc);
        m1 = nm;
    };

    auto rel = [&](const bfu* QA, const bfu* __restrict__ KV,
                   const int* __restrict__ rp, const float* __restrict__ prl) {
        unsigned qu = *(const unsigned*)(QA + (size_t)n * 128 + 2 * l);
        float q0 = bf2f((bfu)qu), q1 = bf2f((bfu)(qu >> 16));
        float ph = prl[h] * scl;
        int i = rp[n], e1 = rp[n + 1];
        for (; i + 3 < e1; i += 4) {
            int sa = sidx[i], sb = sidx[i + 1], sc2 = sidx[i + 2], sd = sidx[i + 3];
            const bfu* pa = KV + (size_t)sa * 256 + 2 * l;
            const bfu* pb = KV + (size_t)sb * 256 + 2 * l;
            const bfu* pc = KV + (size_t)sc2 * 256 + 2 * l;
            const bfu* pd = KV + (size_t)sd * 256 + 2 * l;
            unsigned ka = *(const unsigned*)pa;
            unsigned kb = *(const unsigned*)pb;
            unsigned kc = *(const unsigned*)pc;
            unsigned kd = *(const unsigned*)pd;
            unsigned va = *(const unsigned*)(pa + 128);
            unsigned vb = *(const unsigned*)(pb + 128);
            unsigned vc = *(const unsigned*)(pc + 128);
            unsigned vd = *(const unsigned*)(pd + 128);
            float s0 = fmaf(bf2f((bfu)ka), q0, bf2f((bfu)(ka >> 16)) * q1);
            float s1 = fmaf(bf2f((bfu)kb), q0, bf2f((bfu)(kb >> 16)) * q1);
            float s2 = fmaf(bf2f((bfu)kc), q0, bf2f((bfu)(kc >> 16)) * q1);
            float s3 = fmaf(bf2f((bfu)kd), q0, bf2f((bfu)(kd >> 16)) * q1);
            #pragma unroll
            for (int off = 1; off <= 8; off <<= 1) {
                s0 += __shfl_xor(s0, off);
                s1 += __shfl_xor(s1, off);
                s2 += __shfl_xor(s2, off);
                s3 += __shfl_xor(s3, off);
            }
            upd0(s0 * ph, va);
            upd1(s1 * ph, vb);
            upd0(s2 * ph, vc);
            upd1(s3 * ph, vd);
        }
        for (; i < e1; ++i) {
            int sa = sidx[i];
            const bfu* pa = KV + (size_t)sa * 256 + 2 * l;
            unsigned ka = *(const unsigned*)pa;
            unsigned va = *(const unsigned*)(pa + 128);
            float s0 = fmaf(bf2f((bfu)ka), q0, bf2f((bfu)(ka >> 16)) * q1);
            #pragma unroll
            for (int off = 1; off <= 8; off <<= 1) s0 += __shfl_xor(s0, off);
            upd0(s0 * ph, va);
        }
    };
    rel(QAA, KVA, rpA, prlA);
    rel(QAB, KVB, rpB, prlB);

    // merge the two chains
    float nm = fmaxf(m0, m1);
    float sA = __expf(m0 - nm), sB = __expf(m1 - nm);
    float d = d0 * sA + d1 * sB;
    float a0 = x0 * sA + x1 * sB;
    float a1 = y0 * sA + y1 * sB;

    float rd = 1.f / fmaxf(d, 1e-16f);
    float o0 = gelu_f(a0 * rd);
    float o1 = gelu_f(a1 * rd);
    unsigned ou = ((unsigned)f2bf(o0)) | (((unsigned)f2bf(o1)) << 16);
    *(unsigned*)(ACC + (size_t)n * 128 + 2 * l) = ou;
}

// ---- layer epilogue: plain A (already gelu'd); out-proj; skip+LN+relu; bf16 out ----
__global__ __launch_bounds__(256) void mgemm_epi_layer(
    const bfu* __restrict__ A, const bfu* __restrict__ W, const float* __restrict__ bias,
    const bfu* __restrict__ Xr, const float* __restrict__ skp,
    const float* __restrict__ g, const float* __restrict__ bb,
    bfu* __restrict__ Y, int N)
{
    const int tid = threadIdx.x;
    const int wave = tid >> 6, lane = tid & 63;
    const int row16 = lane & 15, kgrp = lane >> 4;
    const int r_base = blockIdx.x * 64 + wave * 16;
    const int arow = r_base + row16;
    f4 acc[8];
    #pragma unroll
    for (int n = 0; n < 8; ++n) acc[n] = (f4){0.f, 0.f, 0.f, 0.f};
    bh8 az = {0, 0, 0, 0, 0, 0, 0, 0};
    #pragma unroll
    for (int kb = 0; kb < 4; ++kb) {
        bh8 a = az;
        if (arow < N) a = *(const bh8*)(A + (size_t)arow * 128 + kb * 32 + kgrp * 8);
        #pragma unroll
        for (int n = 0; n < 8; ++n) {
            bh8 bv = *(const bh8*)(W + (size_t)(n * 16 + row16) * 128 + kb * 32 + kgrp * 8);
            acc[n] = __builtin_amdgcn_mfma_f32_16x16x32_bf16(a, bv, acc[n], 0, 0, 0);
        }
    }
    const int crow0 = r_base + kgrp * 4;
    float sg = 1.f / (1.f + expf(-skp[0]));
    float z[8][4];
    #pragma unroll
    for (int n = 0; n < 8; ++n) {
        float bn = bias[n * 16 + row16];
        #pragma unroll
        for (int j = 0; j < 4; ++j) z[n][j] = acc[n][j] + bn;
    }
    #pragma unroll
    for (int j = 0; j < 4; ++j) {
        int row = crow0 + j;
        if (row >= N) continue;
        #pragma unroll
        for (int n = 0; n < 8; ++n) {
            float xr = bf2f(Xr[(size_t)row * 128 + n * 16 + row16]);
            z[n][j] = sg * z[n][j] + (1.f - sg) * xr + xr;
        }
    }
    float s[4], q[4];
    #pragma unroll
    for (int j = 0; j < 4; ++j) {
        s[j] = 0.f; q[j] = 0.f;
        #pragma unroll
        for (int n = 0; n < 8; ++n) { s[j] += z[n][j]; q[j] += z[n][j] * z[n][j]; }
    }
    #pragma unroll
    for (int off = 1; off <= 8; off <<= 1) {
        #pragma unroll
        for (int j = 0; j < 4; ++j) {
            s[j] += __shfl_xor(s[j], off);
            q[j] += __shfl_xor(q[j], off);
        }
    }
    #pragma unroll
    for (int j = 0; j < 4; ++j) {
        int row = crow0 + j;
        if (row >= N) continue;
        float mean = s[j] * (1.f / 128.f);
        float var = q[j] * (1.f / 128.f) - mean * mean;
        float inv = rsqrtf(var + 1e-5f);
        #pragma unroll
        for (int n = 0; n < 8; ++n) {
            int col = n * 16 + row16;
            float y = (z[n][j] - mean) * inv * g[col] + bb[col];
            Y[(size_t)row * 128 + col] = f2bf(fmaxf(y, 0.f));
        }
    }
}

// ---- fusion final: out-proj; LN; f32 out ----
__global__ __launch_bounds__(256) void mgemm_epi_ln(
    const bfu* __restrict__ X, const bfu* __restrict__ W, const float* __restrict__ bias,
    const float* __restrict__ g, const float* __restrict__ bb,
    float* __restrict__ Y, int N)
{
    const int tid = threadIdx.x;
    const int wave = tid >> 6, lane = tid & 63;
    const int row16 = lane & 15, kgrp = lane >> 4;
    const int r_base = blockIdx.x * 64 + wave * 16;
    const int arow = r_base + row16;
    f4 acc[8];
    #pragma unroll
    for (int n = 0; n < 8; ++n) acc[n] = (f4){0.f, 0.f, 0.f, 0.f};
    bh8 az = {0, 0, 0, 0, 0, 0, 0, 0};
    #pragma unroll
    for (int kb = 0; kb < 4; ++kb) {
        bh8 a = az;
        if (arow < N) a = *(const bh8*)(X + (size_t)arow * 128 + kb * 32 + kgrp * 8);
        #pragma unroll
        for (int n = 0; n < 8; ++n) {
            bh8 bv = *(const bh8*)(W + (size_t)(n * 16 + row16) * 128 + kb * 32 + kgrp * 8);
            acc[n] = __builtin_amdgcn_mfma_f32_16x16x32_bf16(a, bv, acc[n], 0, 0, 0);
        }
    }
    const int crow0 = r_base + kgrp * 4;
    float z[8][4];
    #pragma unroll
    for (int n = 0; n < 8; ++n) {
        float bn = bias[n * 16 + row16];
        #pragma unroll
        for (int j = 0; j < 4; ++j) z[n][j] = acc[n][j] + bn;
    }
    float s[4], q[4];
    #pragma unroll
    for (int j = 0; j < 4; ++j) {
        s[j] = 0.f; q[j] = 0.f;
        #pragma unroll
        for (int n = 0; n < 8; ++n) { s[j] += z[n][j]; q[j] += z[n][j] * z[n][j]; }
    }
    #pragma unroll
    for (int off = 1; off <= 8; off <<= 1) {
        #pragma unroll
        for (int j = 0; j < 4; ++j) {
            s[j] += __shfl_xor(s[j], off);
            q[j] += __shfl_xor(q[j], off);
        }
    }
    #pragma unroll
    for (int j = 0; j < 4; ++j) {
        int row = crow0 + j;
        if (row >= N) continue;
        float mean = s[j] * (1.f / 128.f);
        float var = q[j] * (1.f / 128.f) - mean * mean;
        float inv = rsqrtf(var + 1e-5f);
        #pragma unroll
        for (int n = 0; n < 8; ++n) {
            int col = n * 16 + row16;
            Y[(size_t)row * 128 + col] = (z[n][j] - mean) * inv * g[col] + bb[col];
        }
    }
}

// ---- fusion attention (3 tokens, 4 heads), wave per node, bf16 out ----
__global__ __launch_bounds__(256) void attn_fuse(
    const bfu* __restrict__ QKV, bfu* __restrict__ OM, int M)
{
    int n = blockIdx.x * 4 + (threadIdx.x >> 6);
    int l = threadIdx.x & 63;
    if (n >= M) return;
    const bfu* base = QKV + (size_t)n * 1152;
    float q[3][2], k[3][2], v[3][2];
    #pragma unroll
    for (int p = 0; p < 3; ++p) {
        q[p][0] = bf2f(base[(0 * 3 + p) * 128 + l]);
        q[p][1] = bf2f(base[(0 * 3 + p) * 128 + l + 64]);
        k[p][0] = bf2f(base[(1 * 3 + p) * 128 + l]);
        k[p][1] = bf2f(base[(1 * 3 + p) * 128 + l + 64]);
        v[p][0] = bf2f(base[(2 * 3 + p) * 128 + l]);
        v[p][1] = bf2f(base[(2 * 3 + p) * 128 + l + 64]);
    }
    float lgA[3][3], lgB[3][3];
    #pragma unroll
    for (int qi = 0; qi < 3; ++qi)
        #pragma unroll
        for (int ki = 0; ki < 3; ++ki) {
            float s0 = q[qi][0] * k[ki][0];
            float s1 = q[qi][1] * k[ki][1];
            #pragma unroll
            for (int off = 1; off <= 16; off <<= 1) {
                s0 += __shfl_xor(s0, off);
                s1 += __shfl_xor(s1, off);
            }
            lgA[qi][ki] = s0 * 0.17677669529663687f;
            lgB[qi][ki] = s1 * 0.17677669529663687f;
        }
    float oA = 0.f, oB = 0.f;
    #pragma unroll
    for (int qi = 0; qi < 3; ++qi) {
        float mA = fmaxf(lgA[qi][0], fmaxf(lgA[qi][1], lgA[qi][2]));
        float e0 = __expf(lgA[qi][0] - mA), e1 = __expf(lgA[qi][1] - mA), e2 = __expf(lgA[qi][2] - mA);
        float rd = 1.f / (e0 + e1 + e2);
        oA += (e0 * v[0][0] + e1 * v[1][0] + e2 * v[2][0]) * rd;
        float mB = fmaxf(lgB[qi][0], fmaxf(lgB[qi][1], lgB[qi][2]));
        float f0 = __expf(lgB[qi][0] - mB), f1 = __expf(lgB[qi][1] - mB), f2 = __expf(lgB[qi][2] - mB);
        float rdB = 1.f / (f0 + f1 + f2);
        oB += (f0 * v[0][1] + f1 * v[1][1] + f2 * v[2][1]) * rdB;
    }
    OM[(size_t)n * 128 + l] = f2bf(oA * (1.f / 3.f));
    OM[(size_t)n * 128 + l + 64] = f2bf(oB * (1.f / 3.f));
}

extern "C" void kernel_launch(void* const* d_in, const int* in_sizes, int n_in,
                              void* d_out, int out_size, void* d_ws, size_t ws_size,
                              hipStream_t stream)
{
    const float* x_pest   = (const float*)d_in[0];
    const float* x_dis    = (const float*)d_in[1];
    const float* x_plant  = (const float*)d_in[2];
    const int*   edges    = (const int*)d_in[3];
    const float* proj_W   = (const float*)d_in[4];
    const float* proj_b   = (const float*)d_in[5];
    const float* event_emb= (const float*)d_in[6];
    const float* kqv_W    = (const float*)d_in[7];
    const float* kqv_b    = (const float*)d_in[8];
    const float* out_W    = (const float*)d_in[9];
    const float* out_b    = (const float*)d_in[10];
    const float* skip     = (const float*)d_in[11];
    const float* a_rel    = (const float*)d_in[12];
    const float* m_rel    = (const float*)d_in[13];
    const float* p_rel    = (const float*)d_in[14];
    const float* blk_ln_g = (const float*)d_in[15];
    const float* blk_ln_b = (const float*)d_in[16];
    const float* fin_W    = (const float*)d_in[17];
    const float* fin_b    = (const float*)d_in[18];
    const float* fout_W   = (const float*)d_in[19];
    const float* fout_b   = (const float*)d_in[20];
    const float* f_ln_g   = (const float*)d_in[21];
    const float* f_ln_b   = (const float*)d_in[22];
    float* out = (float*)d_out;

    static const int NT[4]  = {30000, 20000, 25000, 50000};
    static const int OFF[4] = {0, 30000, 50000, 75000};
    static const int RPOFF[9] = {0, 20001, 50002, 70003, 95004, 125005, 175006, 200007, 250008};
    static const int DG[4][2][2] = { {{1,1},{4,3}}, {{0,0},{2,2}}, {{3,1},{6,3}}, {{5,0},{7,2}} };

    char* wsb = (char*)d_ws;
    size_t ob = 0;
    auto alc = [&](size_t bytes) -> void* {
        void* p = wsb + ob; ob += (bytes + 255) & ~(size_t)255; return p;
    };
    bfu* LK0  = (bfu*)alc((size_t)75000 * 128 * 2);
    bfu* LK1  = (bfu*)alc((size_t)75000 * 128 * 2);
    bfu* POOL = (bfu*)alc((size_t)210000 * 128 * 2);   // QA_A/QA_B/KV pool; fusion QKV; CUR
    bfu* WQAB = (bfu*)alc((size_t)8 * 16384 * 2);
    float* BQA = (float*)alc((size_t)8 * 128 * 4);
    bfu* WVMB = (bfu*)alc((size_t)8 * 16384 * 2);
    float* BVM = (float*)alc((size_t)8 * 128 * 4);
    bfu* KWB  = (bfu*)alc((size_t)12 * 16384 * 2);
    bfu* OWB  = (bfu*)alc((size_t)12 * 16384 * 2);
    bfu* FINWB = (bfu*)alc((size_t)3 * 49152 * 2);
    bfu* FOUTWB = (bfu*)alc((size_t)3 * 16384 * 2);
    bfu* PJWB = (bfu*)alc((size_t)3 * 8192 * 2);
    int* RP   = (int*)alc((size_t)250008 * 4);
    int* PART = (int*)alc(1024);
    u16* SIDX = (u16*)alc((size_t)8 * E_CNT * 2);
    if (ws_size < ob) {
        fill_val<<<(out_size + 255) / 256, 256, 0, stream>>>(out, out_size, 1e30f);
        return;
    }
    int* CUR = (int*)POOL;       // CSR counters (1.6MB), used before pool
    bfu* QKVf = POOL;            // fusion QKV (CH*1152*2 <= 46.08MB <= 53.76MB)
    bfu* OMB  = POOL + (size_t)20000 * 1152;  // attn out (5.12MB, ends at 51.2MB)

    // d_out overlay (time-disjoint): EVB [0,12.8M); XB [12.8,32.0M); L2F [19.2,38.4M)
    bfu* EVB = (bfu*)out;
    bfu* XB  = (bfu*)((char*)out + 12800000);
    bfu* L2F = (bfu*)((char*)out + 19200000);

    cvt_pack<<<(1753600 + 255) / 256, 256, 0, stream>>>(
        out_W, kqv_W, fin_W, fout_W, event_emb, proj_W,
        OWB, KWB, FINWB, FOUTWB, EVB, PJWB);

    // ---- CSR build ----
    hipMemsetAsync(RP, 0, (size_t)250008 * 4, stream);
    const int eg8 = (8 * E_CNT + 255) / 256;
    hist_all<<<eg8, 256, 0, stream>>>(edges, RP);
    scan_part<<<245, 1024, 0, stream>>>(RP, PART, 250008);
    scan_tot<<<1, 256, 0, stream>>>(PART, 245);
    scan_add<<<244, 1024, 0, stream>>>(RP, PART, 250008);
    hipMemsetAsync(CUR, 0, (size_t)8 * 50000 * 4, stream);
    scatter_all<<<eg8, 256, 0, stream>>>(edges, RP, CUR, SIDX);

    // ---- input projections (one MFMA batch launch) ----
    {
        PBatch pb;
        const float* xin0[3] = {x_pest, x_dis, x_plant};
        int acc = 0;
        for (int t = 0; t < 3; ++t) {
            pb.d[t].X = xin0[t];
            pb.d[t].W = PJWB + (size_t)t * 8192;
            pb.d[t].bias = proj_b + (size_t)t * 128;
            pb.d[t].Y = XB + (size_t)OFF[t] * 128;
            pb.d[t].N = NT[t];
            acc += (NT[t] + 127) / 128;
            pb.d[t].bend = acc;
        }
        mgemm_proj<<<acc, 256, 0, stream>>>(pb);
    }

    auto launch_batch = [&](GDesc* ds, int cnt) {
        GBatch gb;
        int acc = 0;
        for (int i = 0; i < cnt; ++i) {
            gb.d[i] = ds[i];
            acc += (ds[i].N + 127) / 128;
            gb.d[i].bend = acc;
        }
        for (int i = cnt; i < 9; ++i) { gb.d[i] = gb.d[cnt - 1]; gb.d[i].bend = acc; }
        mgemm_batch<<<acc, 256, 0, stream>>>(gb);
    };

    for (int l = 0; l < 3; ++l) {
        const float* kqvW_l = kqv_W + (size_t)l * 12 * 16384;
        const float* kqvb_l = kqv_b + (size_t)l * 12 * 128;
        build_rel<<<64, 256, 0, stream>>>(kqvW_l, kqvb_l,
            a_rel + (size_t)l * 8 * 4096, m_rel + (size_t)l * 8 * 4096,
            WQAB, BQA, WVMB, BVM);

        auto feat_ptr = [&](int tt) -> const bfu* {
            if (tt == 3) return EVB;
            if (l == 0) return XB + (size_t)OFF[tt] * 128;
            return (l == 1 ? LK0 : LK1) + (size_t)OFF[tt] * 128;
        };

        int nord = (l == 2) ? 3 : 4;
        for (int dt = 0; dt < nord; ++dt) {
            int Ndt = NT[dt];
            int rA = DG[dt][0][0], sA = DG[dt][0][1];
            int rB = DG[dt][1][0], sB = DG[dt][1][1];
            int NsA = NT[sA], NsB = NT[sB];
            // pool layout: QA_A[Ndt][128] | QA_B[Ndt][128] | KV_A[NsA][256] | KV_B[NsB][256]
            bfu* QA_A = POOL;
            bfu* QA_B = QA_A + (size_t)Ndt * 128;
            bfu* KV_A = QA_B + (size_t)Ndt * 128;
            bfu* KV_B = KV_A + (size_t)NsA * 256;

            GDesc ds[6];
            ds[0] = { feat_ptr(dt), WQAB + (size_t)rA * 16384, BQA + (size_t)rA * 128, QA_A, Ndt, 128, 0 };
            ds[1] = { feat_ptr(dt), WQAB + (size_t)rB * 16384, BQA + (size_t)rB * 128, QA_B, Ndt, 128, 0 };
            ds[2] = { feat_ptr(sA), KWB + (size_t)(l * 4 + sA) * 16384,
                      kqvb_l + ((size_t)sA * 3 + 0) * 128, KV_A, NsA, 256, 0 };
            ds[3] = { feat_ptr(sA), WVMB + (size_t)rA * 16384, BVM + (size_t)rA * 128, KV_A + 128, NsA, 256, 0 };
            ds[4] = { feat_ptr(sB), KWB + (size_t)(l * 4 + sB) * 16384,
                      kqvb_l + ((size_t)sB * 3 + 0) * 128, KV_B, NsB, 256, 0 };
            ds[5] = { feat_ptr(sB), WVMB + (size_t)rB * 16384, BVM + (size_t)rB * 128, KV_B + 128, NsB, 256, 0 };
            launch_batch(ds, 6);

            agg_dual<<<(Ndt + 3) / 4, 256, 0, stream>>>(
                QA_A, QA_B, KV_A, KV_B,
                RP + RPOFF[rA], RP + RPOFF[rB], SIDX,
                p_rel + (size_t)(l * 8 + rA) * 4, p_rel + (size_t)(l * 8 + rB) * 4,
                QA_A /*ACC alias*/, Ndt);

            size_t wi = (size_t)l * 4 + dt;
            const bfu* xr = feat_ptr(dt);
            bfu* ydst = (dt == 3) ? EVB :
                        (l == 0 ? LK0 : (l == 1 ? LK1 : L2F)) + (size_t)OFF[dt] * 128;
            mgemm_epi_layer<<<(Ndt + 63) / 64, 256, 0, stream>>>(
                QA_A, OWB + wi * 16384, out_b + wi * 128, xr, skip + wi,
                blk_ln_g + (size_t)l * 128, blk_ln_b + (size_t)l * 128, ydst, Ndt);
        }
    }

    // ---- fusion heads ----
    const int CH = 20000;
    for (int j = 0; j < 3; ++j) {
        int Nj = NT[j];
        for (int b0 = 0; b0 < Nj; b0 += CH) {
            int M = min(CH, Nj - b0);
            const bfu* srcs[3] = {
                LK0 + (size_t)(OFF[j] + b0) * 128,
                LK1 + (size_t)(OFF[j] + b0) * 128,
                L2F + (size_t)(OFF[j] + b0) * 128 };
            GDesc ds[9];
            int di = 0;
            for (int kk = 0; kk < 3; ++kk)
                for (int p = 0; p < 3; ++p) {
                    ds[di++] = { srcs[p], FINWB + (size_t)j * 49152 + (size_t)kk * 16384,
                                 fin_b + (size_t)j * 384 + kk * 128,
                                 QKVf + (size_t)(kk * 3 + p) * 128, M, 1152, 0 };
                }
            launch_batch(ds, 9);
            attn_fuse<<<(M + 3) / 4, 256, 0, stream>>>(QKVf, OMB, M);
            mgemm_epi_ln<<<(M + 63) / 64, 256, 0, stream>>>(
                OMB, FOUTWB + (size_t)j * 16384, fout_b + (size_t)j * 128,
                f_ln_g + (size_t)j * 128, f_ln_b + (size_t)j * 128,
                out + (size_t)(OFF[j] + b0) * 128, M);
        }
    }
}